// Round 11
// baseline (1661.971 us; speedup 1.0000x reference)
//
#include <hip/hip_runtime.h>
#include <hip/hip_cooperative_groups.h>
#include <math.h>

namespace cg = cooperative_groups;

#define HW 16384
constexpr int C_ = 96;
constexpr int E_ = 192, DI_ = 384, NS_ = 16, R_ = 12, K_ = 4, NBLK_ = 8, GW_ = 48;
constexpr int L_ = 1024, CXP_ = 44; // R + 2*NS
constexpr int TC_ = 64;             // scan chunk length
constexpr int NCH_ = L_ / TC_;      // 16 chunks
constexpr int PCH_ = 130*132;       // padded conv channel size

__device__ __forceinline__ float lrelu_(float x){ return x >= 0.f ? x : 0.2f*x; }
__device__ __forceinline__ float sigmoid_(float x){ return 1.f/(1.f+expf(-x)); }
__device__ __forceinline__ float silu_(float x){ return x/(1.f+expf(-x)); }
__device__ __forceinline__ float softplus_(float x){ return fmaxf(x,0.f)+log1pf(expf(-fabsf(x))); }

// 16-lane row sum via DPP row_shr adds (VALU only, no LDS). Lane 15 of each
// 16-lane row ends with the full row sum. bound_ctrl=0-fill keeps rows independent.
__device__ __forceinline__ float rowsum16_(float p){
  int q;
  q = __builtin_amdgcn_update_dpp(0, __float_as_int(p), 0x111, 0xf, 0xf, true); p += __int_as_float(q);
  q = __builtin_amdgcn_update_dpp(0, __float_as_int(p), 0x112, 0xf, 0xf, true); p += __int_as_float(q);
  q = __builtin_amdgcn_update_dpp(0, __float_as_int(p), 0x114, 0xf, 0xf, true); p += __int_as_float(q);
  q = __builtin_amdgcn_update_dpp(0, __float_as_int(p), 0x118, 0xf, 0xf, true); p += __int_as_float(q);
  return p;
}

// 64-lane wave sum via DPP (row_shr + row_bcast); lane 63 holds the full sum.
__device__ __forceinline__ float wsum64_(float v){
  int q;
  q = __builtin_amdgcn_update_dpp(0, __float_as_int(v), 0x111, 0xf, 0xf, true); v += __int_as_float(q);
  q = __builtin_amdgcn_update_dpp(0, __float_as_int(v), 0x112, 0xf, 0xf, true); v += __int_as_float(q);
  q = __builtin_amdgcn_update_dpp(0, __float_as_int(v), 0x114, 0xf, 0xf, true); v += __int_as_float(q);
  q = __builtin_amdgcn_update_dpp(0, __float_as_int(v), 0x118, 0xf, 0xf, true); v += __int_as_float(q);
  q = __builtin_amdgcn_update_dpp(0, __float_as_int(v), 0x142, 0xa, 0xf, true); v += __int_as_float(q);
  q = __builtin_amdgcn_update_dpp(0, __float_as_int(v), 0x143, 0xc, 0xf, true); v += __int_as_float(q);
  return v;
}

// 64-lane wave max via DPP; lane 63 holds the full max (old=self keeps identity).
__device__ __forceinline__ float wmax64_(float v){
  int q;
  q = __builtin_amdgcn_update_dpp(__float_as_int(v), __float_as_int(v), 0x111, 0xf, 0xf, false); v = fmaxf(v, __int_as_float(q));
  q = __builtin_amdgcn_update_dpp(__float_as_int(v), __float_as_int(v), 0x112, 0xf, 0xf, false); v = fmaxf(v, __int_as_float(q));
  q = __builtin_amdgcn_update_dpp(__float_as_int(v), __float_as_int(v), 0x114, 0xf, 0xf, false); v = fmaxf(v, __int_as_float(q));
  q = __builtin_amdgcn_update_dpp(__float_as_int(v), __float_as_int(v), 0x118, 0xf, 0xf, false); v = fmaxf(v, __int_as_float(q));
  q = __builtin_amdgcn_update_dpp(__float_as_int(v), __float_as_int(v), 0x142, 0xa, 0xf, false); v = fmaxf(v, __int_as_float(q));
  q = __builtin_amdgcn_update_dpp(__float_as_int(v), __float_as_int(v), 0x143, 0xc, 0xf, false); v = fmaxf(v, __int_as_float(q));
  return v;
}

// ---------------- all 4 weight transposes + SCPA weight repack + dtw transpose
__global__ void k_transAll(const float* __restrict__ peW, float* __restrict__ peWT,
                           const float* __restrict__ puW, float* __restrict__ puWT,
                           const float* __restrict__ inW, float* __restrict__ inWT,
                           const float* __restrict__ outW, float* __restrict__ outWT,
                           const float* __restrict__ k1w, const float* __restrict__ k3w,
                           const float* __restrict__ k2w, const float* __restrict__ k4w,
                           const float* __restrict__ c1a, const float* __restrict__ c1b,
                           const float* __restrict__ c3w, const float* __restrict__ dtw,
                           float* __restrict__ rpD, float* __restrict__ rp3,
                           float* __restrict__ r1, float* __restrict__ r3,
                           float* __restrict__ dtwT){
  __shared__ float t[32][33];
  int id = blockIdx.x;
  if (id >= 2304){
    int idx = (id-2304)*256 + threadIdx.y*32 + threadIdx.x;
    if (idx < 49152){
      int y = idx/1536, r = idx%1536, ic = r>>5, j = r&31;
      float v = 0.f;
      if (y < 16){
        if (j < 27) v = k1w[((size_t)((y*3 + j/9)*48 + ic))*9 + j%9];
      } else {
        int g = y-16;
        if (j < 27) v = k3w[((size_t)((g*3 + j/9)*48 + ic))*9 + j%9];
        else if (j < 30) v = k2w[(size_t)(g*3 + (j-27))*48 + ic];
      }
      rpD[idx] = v;
    } else if (idx < 72192){
      int tt = idx - 49152;
      int y = tt/960, rem = tt%960, ic = rem/20, j = rem%20;
      float v = 0.f;
      if (j < 18) v = k4w[((size_t)((y*2 + j/9)*48 + ic))*9 + j%9];
      rp3[tt] = v;
    } else if (idx < 81408){
      int tt = idx - 72192;
      int g = tt/1152, r = tt%1152, ic = r/12, j = r%12;
      r1[tt] = (j<6) ? c1a[(size_t)(g*6+j)*96+ic] : c1b[(size_t)(g*6+j-6)*96+ic];
    } else if (idx < 90624){
      int tt = idx - 81408;
      int g = tt/1152, r = tt%1152, ic = r/12, j = r%12;
      r3[tt] = c3w[(size_t)(g*12+j)*96+ic];
    } else if (idx < 238080){
      int tt = idx - 90624;
      int b = tt/18432, rem = tt%18432;
      int k = rem/4608, rem2 = rem%4608, r = rem2/384, d = rem2%384;
      dtwT[tt] = dtw[(((size_t)(b*4 + k)*384 + d))*12 + r];
    }
    return;
  }
  const float* in; float* out; int rows, cols, bx, by;
  if (id < 288){ in=peW; out=peWT; rows=192; cols=1536; bx=id%48; by=id/48; }
  else if (id < 576){ int r=id-288; in=puW; out=puWT; rows=1536; cols=192; bx=r%6; by=r/6; }
  else if (id < 1728){ int r=id-576; int z=r/144; int q=r%144;
    in=inW+(size_t)z*768*192; out=inWT+(size_t)z*768*192; rows=768; cols=192; bx=q%6; by=q/6; }
  else { int r=id-1728; int z=r/72; int q=r%72;
    in=outW+(size_t)z*192*384; out=outWT+(size_t)z*192*384; rows=192; cols=384; bx=q%12; by=q/12; }
  int r0=by*32, c0=bx*32, tx=threadIdx.x, ty=threadIdx.y;
  for (int i=0;i<32;i+=8){
    int r=r0+ty+i, c=c0+tx;
    if (r<rows && c<cols) t[ty+i][tx]=in[(size_t)r*cols+c];
  }
  __syncthreads();
  for (int i=0;i<32;i+=8){
    int c=c0+ty+i, r=r0+tx;
    if (r<rows && c<cols) out[(size_t)c*rows+r]=t[tx][ty+i];
  }
}

// ---------------- bn1 + per-channel mean/max stats; also zeroes LN-sum buffers
__global__ void k_bn1(const float* __restrict__ x, const float* g, const float* b,
                      const float* m, const float* v,
                      float* __restrict__ h, float* __restrict__ stats,
                      float* __restrict__ su, float* __restrict__ sq){
  int c = blockIdx.x, tid = threadIdx.x;
  int gid = c*256 + tid;
  if (gid < 1024){ su[gid] = 0.f; sq[gid] = 0.f; }
  float sc = g[c]*rsqrtf(v[c]+1e-5f), sh = b[c]-m[c]*sc;
  const float* xc = x + (size_t)c*HW;
  float* hc = h + (size_t)c*HW;
  float s = 0.f, mx = -1e30f;
  for (int i=tid;i<HW;i+=256){
    float val = fmaf(xc[i], sc, sh);
    hc[i] = val; s += val; mx = fmaxf(mx, val);
  }
  s = wsum64_(s); mx = wmax64_(mx);
  __shared__ float ss[4], sm[4];
  int wid = tid>>6, lane = tid&63;
  if (lane==63){ ss[wid]=s; sm[wid]=mx; }
  __syncthreads();
  if (!tid){
    stats[c] = (ss[0]+ss[1]+ss[2]+ss[3])*(1.f/HW);
    stats[96+c] = fmaxf(fmaxf(sm[0],sm[1]),fmaxf(sm[2],sm[3]));
  }
}

// ---------------- pe GEMM: A = patchified bufH (fused addressing), + bias + LN-stat atomics
__global__ __launch_bounds__(256) void k_gemmPE(const float* __restrict__ hsrc,
                      const float* __restrict__ wt, const float* __restrict__ bias,
                      float* __restrict__ out, float* __restrict__ su, float* __restrict__ sq){
  const int K = 1536, N = 192;
  __shared__ float As[32][34];
  __shared__ float Bs[32][32];
  int tid = threadIdx.x;
  int m0 = blockIdx.x*32, n0 = blockIdx.y*32;
  int tx = tid&15, ty = tid>>4;
  int arow = tid>>3, akq = tid&7;
  int brow = tid>>3, bn4 = tid&7;
  int m = m0+arow;
  int base2 = (m>>5)*512 + (m&31)*4;
  auto aload = [&](int kk)->float4 {
    int c = kk>>4, i2 = (kk>>2)&3;
    return *(const float4*)&hsrc[((size_t)c<<14) + (size_t)(i2*128 + base2)];
  };
  float4 aR = aload(akq*4);
  float4 bR = *(const float4*)&wt[(size_t)brow*N + n0 + bn4*4];
  float acc[2][2] = {{0}};
  for (int k0=0; k0<K; k0+=32){
    __syncthreads();
    As[akq*4+0][arow]=aR.x; As[akq*4+1][arow]=aR.y;
    As[akq*4+2][arow]=aR.z; As[akq*4+3][arow]=aR.w;
    *(float4*)&Bs[brow][bn4*4] = bR;
    __syncthreads();
    if (k0+32 < K){
      aR = aload(k0+32+akq*4);
      bR = *(const float4*)&wt[(size_t)(k0+32+brow)*N + n0 + bn4*4];
    }
    #pragma unroll
    for (int kk=0; kk<32; kk++){
      float2 av = *(const float2*)&As[kk][ty*2];
      float2 bv = *(const float2*)&Bs[kk][tx*2];
      acc[0][0] = fmaf(av.x, bv.x, acc[0][0]);
      acc[0][1] = fmaf(av.x, bv.y, acc[0][1]);
      acc[1][0] = fmaf(av.y, bv.x, acc[1][0]);
      acc[1][1] = fmaf(av.y, bv.y, acc[1][1]);
    }
  }
  float2 bq = *(const float2*)&bias[n0+tx*2];
  float sl[2], ql[2];
  #pragma unroll
  for (int i=0;i<2;i++){
    size_t o = (size_t)(m0+ty*2+i)*N + n0 + tx*2;
    float2 ov; ov.x = acc[i][0]+bq.x; ov.y = acc[i][1]+bq.y;
    *(float2*)&out[o] = ov;
    sl[i] = ov.x+ov.y; ql[i] = ov.x*ov.x+ov.y*ov.y;
  }
  sl[0] = rowsum16_(sl[0]); ql[0] = rowsum16_(ql[0]);
  sl[1] = rowsum16_(sl[1]); ql[1] = rowsum16_(ql[1]);
  if (tx==15){
    atomicAdd(&su[m0+ty*2],   sl[0]); atomicAdd(&sq[m0+ty*2],   ql[0]);
    atomicAdd(&su[m0+ty*2+1], sl[1]); atomicAdd(&sq[m0+ty*2+1], ql[1]);
  }
}

// ---------------- gemm32 + residual + LN-stat atomics (outproj); grid (M/32,N/32)
__global__ __launch_bounds__(256) void k_gemm32s(const float* __restrict__ act,
                      const float* __restrict__ wt, const float* __restrict__ res,
                      float* __restrict__ out, float* __restrict__ su, float* __restrict__ sq,
                      int K, int N){
  __shared__ float As[32][34];
  __shared__ float Bs[32][32];
  int tid = threadIdx.x;
  int m0 = blockIdx.x*32, n0 = blockIdx.y*32;
  int tx = tid&15, ty = tid>>4;
  int arow = tid>>3, akq = tid&7;
  int brow = tid>>3, bn4 = tid&7;
  float4 aR = *(const float4*)&act[(size_t)(m0+arow)*K + akq*4];
  float4 bR = *(const float4*)&wt [(size_t)brow*N + n0 + bn4*4];
  float acc[2][2] = {{0}};
  for (int k0=0; k0<K; k0+=32){
    __syncthreads();
    As[akq*4+0][arow]=aR.x; As[akq*4+1][arow]=aR.y;
    As[akq*4+2][arow]=aR.z; As[akq*4+3][arow]=aR.w;
    *(float4*)&Bs[brow][bn4*4] = bR;
    __syncthreads();
    if (k0+32 < K){
      aR = *(const float4*)&act[(size_t)(m0+arow)*K + k0+32 + akq*4];
      bR = *(const float4*)&wt [(size_t)(k0+32+brow)*N + n0 + bn4*4];
    }
    #pragma unroll
    for (int kk=0; kk<32; kk++){
      float2 av = *(const float2*)&As[kk][ty*2];
      float2 bv = *(const float2*)&Bs[kk][tx*2];
      acc[0][0] = fmaf(av.x, bv.x, acc[0][0]);
      acc[0][1] = fmaf(av.x, bv.y, acc[0][1]);
      acc[1][0] = fmaf(av.y, bv.x, acc[1][0]);
      acc[1][1] = fmaf(av.y, bv.y, acc[1][1]);
    }
  }
  float sl[2], ql[2];
  #pragma unroll
  for (int i=0;i<2;i++){
    size_t o = (size_t)(m0+ty*2+i)*N + n0 + tx*2;
    float2 r = *(const float2*)&res[o];
    float2 ov; ov.x = acc[i][0]+r.x; ov.y = acc[i][1]+r.y;
    *(float2*)&out[o] = ov;
    sl[i] = ov.x+ov.y; ql[i] = ov.x*ov.x+ov.y*ov.y;
  }
  sl[0] = rowsum16_(sl[0]); ql[0] = rowsum16_(ql[0]);
  sl[1] = rowsum16_(sl[1]); ql[1] = rowsum16_(ql[1]);
  if (tx==15){
    atomicAdd(&su[m0+ty*2],   sl[0]); atomicAdd(&sq[m0+ty*2],   ql[0]);
    atomicAdd(&su[m0+ty*2+1], sl[1]); atomicAdd(&sq[m0+ty*2+1], ql[1]);
  }
}

// ---------------- pu GEMM (32x64 tile, 2x4 acc) + bias + residual-sum + attn + bn2
// grid (32, 24), tb 256
__global__ __launch_bounds__(256) void k_gemmPUs(const float* __restrict__ act,
                      const float* __restrict__ wt, const float* __restrict__ bias,
                      const float* __restrict__ x, const float* __restrict__ bufH,
                      const float* __restrict__ stats, const float* __restrict__ caw1,
                      const float* __restrict__ caw2,
                      const float* __restrict__ g2, const float* __restrict__ b2,
                      const float* __restrict__ m2, const float* __restrict__ v2,
                      float* __restrict__ xsum, float* __restrict__ h2){
  const int K = 192, N = 1536;
  __shared__ float As[32][34];
  __shared__ float Bs[32][68];
  __shared__ float hid_[12];
  int tid = threadIdx.x;
  if (tid < 12){
    int j = tid%6, which = tid/6;
    const float* vv = stats + which*96;
    float a = 0.f;
    for (int c=0;c<96;c++) a += vv[c]*caw1[j*96+c];
    hid_[tid] = fmaxf(a, 0.f);
  }
  int m0 = blockIdx.x*32, n0 = blockIdx.y*64;
  int tx = tid&15, ty = tid>>4;
  int arow = tid>>3, akq = tid&7;
  int brow = tid>>4, bnq = tid&15;
  float4 aR = *(const float4*)&act[(size_t)(m0+arow)*K + akq*4];
  float4 b0 = *(const float4*)&wt[(size_t)brow*N + n0 + bnq*4];
  float4 b1 = *(const float4*)&wt[(size_t)(brow+16)*N + n0 + bnq*4];
  float acc[2][4] = {{0}};
  for (int k0=0; k0<K; k0+=32){
    __syncthreads();
    As[akq*4+0][arow]=aR.x; As[akq*4+1][arow]=aR.y;
    As[akq*4+2][arow]=aR.z; As[akq*4+3][arow]=aR.w;
    *(float4*)&Bs[brow][bnq*4] = b0;
    *(float4*)&Bs[brow+16][bnq*4] = b1;
    __syncthreads();
    if (k0+32 < K){
      aR = *(const float4*)&act[(size_t)(m0+arow)*K + k0+32 + akq*4];
      b0 = *(const float4*)&wt[(size_t)(k0+32+brow)*N + n0 + bnq*4];
      b1 = *(const float4*)&wt[(size_t)(k0+48+brow)*N + n0 + bnq*4];
    }
    #pragma unroll
    for (int kk=0; kk<32; kk++){
      float2 av = *(const float2*)&As[kk][ty*2];
      float4 bv = *(const float4*)&Bs[kk][tx*4];
      acc[0][0] = fmaf(av.x, bv.x, acc[0][0]);
      acc[0][1] = fmaf(av.x, bv.y, acc[0][1]);
      acc[0][2] = fmaf(av.x, bv.z, acc[0][2]);
      acc[0][3] = fmaf(av.x, bv.w, acc[0][3]);
      acc[1][0] = fmaf(av.y, bv.x, acc[1][0]);
      acc[1][1] = fmaf(av.y, bv.y, acc[1][1]);
      acc[1][2] = fmaf(av.y, bv.z, acc[1][2]);
      acc[1][3] = fmaf(av.y, bv.w, acc[1][3]);
    }
  }
  int n = n0 + tx*4;
  float4 bq = *(const float4*)&bias[n];
  int c = n>>4, i2 = (n>>2)&3;
  float at;
  {
    float a = 0.f;
    #pragma unroll
    for (int jj=0;jj<6;jj++) a += (hid_[jj]+hid_[6+jj])*caw2[c*6+jj];
    at = sigmoid_(a);
  }
  float sc2 = g2[c]*rsqrtf(v2[c]+1e-5f);
  float sh2 = b2[c]-m2[c]*sc2;
  #pragma unroll
  for (int i=0;i<2;i++){
    int m = m0+ty*2+i;
    size_t o = ((size_t)c<<14) + (size_t)((m>>5)*4+i2)*128 + (m&31)*4;
    float4 xv = *(const float4*)&x[o];
    float4 hv = *(const float4*)&bufH[o];
    float4 sv;
    sv.x = xv.x + hv.x*at + acc[i][0]+bq.x;
    sv.y = xv.y + hv.y*at + acc[i][1]+bq.y;
    sv.z = xv.z + hv.z*at + acc[i][2]+bq.z;
    sv.w = xv.w + hv.w*at + acc[i][3]+bq.w;
    *(float4*)&xsum[o] = sv;
    float4 h2v;
    h2v.x = fmaf(sv.x, sc2, sh2);
    h2v.y = fmaf(sv.y, sc2, sh2);
    h2v.z = fmaf(sv.z, sc2, sh2);
    h2v.w = fmaf(sv.w, sc2, sh2);
    *(float4*)&h2[o] = h2v;
  }
}

// ---------------- gemm (32x64 tile, 2x4 acc) with layernorm fused on A; grid (32, N/64)
__global__ __launch_bounds__(256) void k_gemm32ln(const float* __restrict__ act,
                      const float* __restrict__ wt, const float* __restrict__ lg,
                      const float* __restrict__ lb, const float* __restrict__ su,
                      const float* __restrict__ sq, float* __restrict__ out,
                      int K, int N){
  __shared__ float As[32][34];
  __shared__ float Bs[32][68];
  int tid = threadIdx.x;
  int m0 = blockIdx.x*32, n0 = blockIdx.y*64;
  int tx = tid&15, ty = tid>>4;
  int arow = tid>>3, akq = tid&7;
  int brow = tid>>4, bnq = tid&15;
  float m = su[m0+arow]*(1.f/192.f);
  float r = rsqrtf(sq[m0+arow]*(1.f/192.f) - m*m + 1e-5f);
  float4 aR = *(const float4*)&act[(size_t)(m0+arow)*K + akq*4];
  float4 gR = *(const float4*)&lg[akq*4];
  float4 hR = *(const float4*)&lb[akq*4];
  float4 b0 = *(const float4*)&wt[(size_t)brow*N + n0 + bnq*4];
  float4 b1 = *(const float4*)&wt[(size_t)(brow+16)*N + n0 + bnq*4];
  float acc[2][4] = {{0}};
  for (int k0=0; k0<K; k0+=32){
    __syncthreads();
    As[akq*4+0][arow] = (aR.x-m)*r*gR.x + hR.x;
    As[akq*4+1][arow] = (aR.y-m)*r*gR.y + hR.y;
    As[akq*4+2][arow] = (aR.z-m)*r*gR.z + hR.z;
    As[akq*4+3][arow] = (aR.w-m)*r*gR.w + hR.w;
    *(float4*)&Bs[brow][bnq*4] = b0;
    *(float4*)&Bs[brow+16][bnq*4] = b1;
    __syncthreads();
    if (k0+32 < K){
      aR = *(const float4*)&act[(size_t)(m0+arow)*K + k0+32 + akq*4];
      gR = *(const float4*)&lg[k0+32+akq*4];
      hR = *(const float4*)&lb[k0+32+akq*4];
      b0 = *(const float4*)&wt[(size_t)(k0+32+brow)*N + n0 + bnq*4];
      b1 = *(const float4*)&wt[(size_t)(k0+48+brow)*N + n0 + bnq*4];
    }
    #pragma unroll
    for (int kk=0; kk<32; kk++){
      float2 av = *(const float2*)&As[kk][ty*2];
      float4 bv = *(const float4*)&Bs[kk][tx*4];
      acc[0][0] = fmaf(av.x, bv.x, acc[0][0]);
      acc[0][1] = fmaf(av.x, bv.y, acc[0][1]);
      acc[0][2] = fmaf(av.x, bv.z, acc[0][2]);
      acc[0][3] = fmaf(av.x, bv.w, acc[0][3]);
      acc[1][0] = fmaf(av.y, bv.x, acc[1][0]);
      acc[1][1] = fmaf(av.y, bv.y, acc[1][1]);
      acc[1][2] = fmaf(av.y, bv.z, acc[1][2]);
      acc[1][3] = fmaf(av.y, bv.w, acc[1][3]);
    }
  }
  #pragma unroll
  for (int i=0;i<2;i++){
    float4 ov;
    ov.x = acc[i][0]; ov.y = acc[i][1]; ov.z = acc[i][2]; ov.w = acc[i][3];
    *(float4*)&out[(size_t)(m0+ty*2+i)*N + n0 + tx*4] = ov;
  }
}

// ---------------- fused depthwise conv + silu + 2-layout xst build; grid (32 h0, 12 d0), tb (32,8)
__global__ __launch_bounds__(256) void k_dwxst(const float* __restrict__ xz,
                        const float* __restrict__ w, const float* __restrict__ bias,
                        float* __restrict__ xcs, float* __restrict__ xst0,
                        float* __restrict__ xst1){
  __shared__ float ld[96][33];
  __shared__ float t[32][33];
  int h0 = blockIdx.x;
  int d0 = blockIdx.y*32;
  int tx = threadIdx.x, ty = threadIdx.y;
  #pragma unroll
  for (int i=0;i<12;i++){
    int ll = i*8 + ty;
    int h = h0 - 1 + (ll>>5);
    int wv = ll & 31;
    float v = 0.f;
    if ((unsigned)h < 32u) v = xz[(size_t)(h*32+wv)*768 + d0 + tx];
    ld[ll][tx] = v;
  }
  __syncthreads();
  #pragma unroll
  for (int i=0;i<4;i++){
    int dl = ty + 8*i;
    int d = d0 + dl;
    float acc = bias[d];
    const float* wp = w + d*9;
    #pragma unroll
    for (int di=0;di<3;di++){
      #pragma unroll
      for (int dj=0;dj<3;dj++){
        int wq = tx + dj - 1;
        if ((unsigned)wq < 32u)
          acc = fmaf(ld[di*32 + wq][dl], wp[di*3+dj], acc);
      }
    }
    float val = silu_(acc);
    xcs[(size_t)d*L_ + h0*32 + tx] = val;
    t[dl][tx] = val;
  }
  __syncthreads();
  int d = d0 + tx;
  #pragma unroll
  for (int i=0;i<4;i++){
    int wq = ty + 8*i;
    int l = h0*32 + wq;
    float val = t[tx][wq];
    int t1 = wq*32 + h0;
    xst0[(size_t)l*DI_ + d] = val;
    xst1[(size_t)t1*DI_ + d] = val;
  }
}

// ---------------- x_dbl partial (split-K over d, 3 x 128): grid (4, 11, 12)
__global__ __launch_bounds__(256) void k_xdblP(const float* __restrict__ xcs,
                       const float* __restrict__ xw, float* __restrict__ xdblP){
  __shared__ float lw[512];
  int kz = blockIdx.z;
  int k = kz & 3, sp = kz >> 2;
  int c0 = blockIdx.y*4;
  int tid = threadIdx.x;
  for (int i=tid; i<512; i+=256){
    int d = i>>2, c = i&3;
    lw[i] = xw[((size_t)k*CXP_ + c0 + c)*DI_ + sp*128 + d];
  }
  __syncthreads();
  int s = blockIdx.x*256 + tid;
  int Ts = ((s&31)<<5) | (s>>5);
  int lwi;
  if (k==0) lwi = s;
  else if (k==1) lwi = Ts;
  else if (k==2) lwi = 1023-s;
  else lwi = 1023-Ts;
  const float* src = xcs + s + (size_t)sp*128*L_;
  float a0=0,a1=0,a2=0,a3=0;
  for (int d=0; d<128; d++){
    float v = src[(size_t)d*L_];
    float4 w4 = *(const float4*)&lw[d*4];
    a0 = fmaf(v, w4.x, a0);
    a1 = fmaf(v, w4.y, a1);
    a2 = fmaf(v, w4.z, a2);
    a3 = fmaf(v, w4.w, a3);
  }
  size_t base = (((size_t)sp*4 + k)*CXP_ + c0)*L_ + lwi;
  xdblP[base]       = a0;
  xdblP[base+L_]    = a1;
  xdblP[base+2*L_]  = a2;
  xdblP[base+3*L_]  = a3;
}

// ---------------- combine partials + dt proj + softplus -> dts_t; repack B,C -> bc
// 4 l per block; psums staged in LDS; coalesced dtwT weights. grid (256, 4), tb 384
__global__ __launch_bounds__(384) void k_dtbc(const float* __restrict__ xdblP,
                       const float* __restrict__ dtwT,
                       const float* __restrict__ dtb, float* __restrict__ dts_t,
                       float* __restrict__ bc){
  __shared__ float psum[4][44];
  int k = blockIdx.y;
  int l0 = blockIdx.x*4;
  int tid = threadIdx.x;
  for (int i=tid; i<176; i+=384){
    int li = i/44, c = i%44;
    int l = l0 + li;
    size_t o0 = ((size_t)(k)*CXP_ + c)*L_ + l;
    size_t o1 = ((size_t)(4+k)*CXP_ + c)*L_ + l;
    size_t o2 = ((size_t)(8+k)*CXP_ + c)*L_ + l;
    psum[li][c] = xdblP[o0] + xdblP[o1] + xdblP[o2];
  }
  __syncthreads();
  int d = tid;
  float w[12];
  #pragma unroll
  for (int r=0;r<R_;r++) w[r] = dtwT[((size_t)k*R_ + r)*DI_ + d];
  float bias = dtb[(size_t)k*DI_ + d];
  #pragma unroll
  for (int li=0; li<4; li++){
    float acc = bias;
    #pragma unroll
    for (int r=0;r<R_;r++) acc = fmaf(psum[li][r], w[r], acc);
    dts_t[((size_t)k*L_ + l0+li)*DI_ + d] = softplus_(acc);
  }
  if (tid < 128){
    int li = tid>>5, d2 = tid&31;
    bc[((size_t)k*L_ + l0+li)*32 + d2] = psum[li][12+d2];
  }
}

// ---------------- fused selective scan (cooperative): stage once, phase A,
// grid sync, carry fold, phase C. grid (16,24,4), tb 256, LDS 16KB.
__global__ __launch_bounds__(256) void k_scanAC(const float* __restrict__ xst0,
                      const float* __restrict__ xst1,
                      const float* __restrict__ dts_t, const float* __restrict__ bc,
                      const float* __restrict__ Alog, float2* __restrict__ eh,
                      float* __restrict__ yst){
  __shared__ float2 sdx[TC_][16];
  __shared__ float2 sbc2[TC_][16];
  int k = blockIdx.z;
  int d0 = blockIdx.y*16;
  int ch = blockIdx.x;
  int tid = threadIdx.x;
  int t0 = ch*TC_;
  const float* xb = (k&1) ? xst1 : xst0;
  for (int i=tid; i<TC_*16; i+=256){
    int t = i>>4, dl = i&15;
    float dtv = dts_t[((size_t)k*L_ + t0+t)*DI_ + d0+dl];
    int l = (k<2) ? (t0+t) : (1023-t0-t);
    float xvv = xb[(size_t)l*DI_ + d0+dl];
    sdx[t][dl] = make_float2(dtv, xvv);
    const float* bcp = bc + ((size_t)k*L_ + t0+t)*32;
    sbc2[t][dl] = make_float2(bcp[dl], bcp[16+dl]);
  }
  __syncthreads();
  int dg = tid>>4;
  int d = d0 + dg;
  int n = tid&15;
  float A = -expf(Alog[((size_t)k*DI_ + d)*NS_ + n]);
  float aL2 = A * 1.4426950408889634f;
  // phase A: per-chunk aggregates with zero carry-in
  float h = 0.f, Ep = 1.f;
  #pragma unroll 8
  for (int t=0;t<TC_;t++){
    float2 dx = sdx[t][dg];
    float e = exp2f(aL2*dx.x);
    h = fmaf(e, h, dx.x*dx.y*sbc2[t][n].x);
    Ep *= e;
  }
  size_t idx = (((size_t)k*NCH_ + ch)*DI_ + d)*NS_ + n;
  eh[idx] = make_float2(Ep, h);
  cg::this_grid().sync();
  // carry fold: packed (E,H) aggregates of preceding chunks
  float hc = 0.f;
  {
    size_t base = (size_t)k*NCH_*DI_*NS_ + (size_t)d*NS_ + n;
    const size_t cs = (size_t)DI_*NS_;
    int c = 0;
    for (; c+4<=ch; c+=4){
      float2 a0 = eh[base+(size_t)c*cs];
      float2 a1 = eh[base+(size_t)(c+1)*cs];
      float2 a2 = eh[base+(size_t)(c+2)*cs];
      float2 a3 = eh[base+(size_t)(c+3)*cs];
      hc = fmaf(a0.x,hc,a0.y); hc = fmaf(a1.x,hc,a1.y);
      hc = fmaf(a2.x,hc,a2.y); hc = fmaf(a3.x,hc,a3.y);
    }
    for (; c<ch; c++){
      float2 a = eh[base+(size_t)c*cs];
      hc = fmaf(a.x, hc, a.y);
    }
  }
  // phase C: recompute with carry-in from the SAME staged tiles, emit y
  h = hc;
  float* yp = yst + ((size_t)k*L_ + t0)*DI_ + d;
  #pragma unroll 8
  for (int t=0;t<TC_;t++){
    float2 dx = sdx[t][dg];
    float2 bcv = sbc2[t][n];
    float e = exp2f(aL2*dx.x);
    h = fmaf(e, h, dx.x*dx.y*bcv.x);
    float p = rowsum16_(h*bcv.y);
    if (n==15) yp[(size_t)t*DI_] = p;
  }
}

// ---------------- merge 4 dirs + Dskip + LN + silu(z) gate; zeroes LN-sum bufs
__global__ void k_merge(const float* __restrict__ yst, const float* __restrict__ xst0,
                        const float* __restrict__ xst1,
                        const float* __restrict__ Dsk, const float* __restrict__ mw,
                        const float* __restrict__ ong, const float* __restrict__ onb,
                        const float* __restrict__ xz, float* __restrict__ out,
                        float* __restrict__ su, float* __restrict__ sq){
  int l = blockIdx.x, d = threadIdx.x;
  if (d == 0){ su[l] = 0.f; sq[l] = 0.f; }
  int T = ((l&31)<<5) | (l>>5);
  int tt[4] = { l, T, 1023-l, 1023-T };
  float xv0 = xst0[(size_t)l*DI_ + d];
  float xv1 = xst1[(size_t)T*DI_ + d];
  float v = 0.f;
  #pragma unroll
  for (int k=0;k<4;k++){
    float xk = (k&1) ? xv1 : xv0;
    v += mw[k]*(yst[(size_t)(k*L_ + tt[k])*DI_ + d] + xk*Dsk[k*DI_+d]);
  }
  float s = wsum64_(v), sqv = wsum64_(v*v);
  __shared__ float rs_[6], rq_[6];
  int lane = d&63, wid = d>>6;
  if (lane==63){ rs_[wid]=s; rq_[wid]=sqv; }
  __syncthreads();
  float ts=0.f, tq=0.f;
  #pragma unroll
  for (int i=0;i<6;i++){ ts += rs_[i]; tq += rq_[i]; }
  float mu = ts*(1.f/DI_);
  float rstd = rsqrtf(tq*(1.f/DI_) - mu*mu + 1e-5f);
  float y = (v-mu)*rstd*ong[d] + onb[d];
  float z = xz[(size_t)l*768 + DI_ + d];
  out[(size_t)l*DI_ + d] = y * silu_(z);
}

// ---------------- scpa: dual 1x1 conv + lrelu; 2px/thread; padded output + border zero
__global__ __launch_bounds__(256) void k_1x1ab(const float* __restrict__ h2,
                        const float* __restrict__ r1,
                        float* __restrict__ padA, float* __restrict__ padB){
  __shared__ float lw[1152];
  int g = blockIdx.y;
  int tid = threadIdx.x;
  for (int i=tid; i<288; i+=256)
    ((float4*)lw)[i] = ((const float4*)(r1 + (size_t)g*1152))[i];
  if (blockIdx.x == 0){
    for (int i=tid; i<6240; i+=256){
      int ch = i/520, rem = i%520;
      int row, col;
      if (rem < 132){ row = 0; col = rem; }
      else if (rem < 264){ row = 129; col = rem-132; }
      else { int rr = rem-264; row = 1 + (rr>>1); col = (rr&1) ? 129 : 0; }
      float* dst = (ch < 6) ? padA : padB;
      int c = g*6 + (ch < 6 ? ch : ch-6);
      dst[(size_t)c*PCH_ + row*132 + col] = 0.f;
    }
  }
  __syncthreads();
  int p0 = (blockIdx.x*256 + tid)*2;
  float acc[2][12];
  #pragma unroll
  for (int i=0;i<2;i++)
    #pragma unroll
    for (int o=0;o<12;o++) acc[i][o]=0.f;
  for (int c=0;c<96;c++){
    float2 v = *(const float2*)&h2[(size_t)c*HW + p0];
    float4 w0 = *(const float4*)&lw[c*12];
    float4 w1 = *(const float4*)&lw[c*12+4];
    float4 w2 = *(const float4*)&lw[c*12+8];
    acc[0][0] = fmaf(v.x, w0.x, acc[0][0]); acc[1][0] = fmaf(v.y, w0.x, acc[1][0]);
    acc[0][1] = fmaf(v.x, w0.y, acc[0][1]); acc[1][1] = fmaf(v.y, w0.y, acc[1][1]);
    acc[0][2] = fmaf(v.x, w0.z, acc[0][2]); acc[1][2] = fmaf(v.y, w0.z, acc[1][2]);
    acc[0][3] = fmaf(v.x, w0.w, acc[0][3]); acc[1][3] = fmaf(v.y, w0.w, acc[1][3]);
    acc[0][4] = fmaf(v.x, w1.x, acc[0][4]); acc[1][4] = fmaf(v.y, w1.x, acc[1][4]);
    acc[0][5] = fmaf(v.x, w1.y, acc[0][5]); acc[1][5] = fmaf(v.y, w1.y, acc[1][5]);
    acc[0][6] = fmaf(v.x, w1.z, acc[0][6]); acc[1][6] = fmaf(v.y, w1.z, acc[1][6]);
    acc[0][7] = fmaf(v.x, w1.w, acc[0][7]); acc[1][7] = fmaf(v.y, w1.w, acc[1][7]);
    acc[0][8] = fmaf(v.x, w2.x, acc[0][8]); acc[1][8] = fmaf(v.y, w2.x, acc[1][8]);
    acc[0][9] = fmaf(v.x, w2.y, acc[0][9]); acc[1][9] = fmaf(v.y, w2.y, acc[1][9]);
    acc[0][10]= fmaf(v.x, w2.z, acc[0][10]); acc[1][10]= fmaf(v.y, w2.z, acc[1][10]);
    acc[0][11]= fmaf(v.x, w2.w, acc[0][11]); acc[1][11]= fmaf(v.y, w2.w, acc[1][11]);
  }
  int row = p0>>7, col = p0&127;
  size_t pb = (size_t)(row+1)*132 + col+1;
  #pragma unroll
  for (int o=0;o<6;o++){
    size_t oa = (size_t)(g*6+o)*PCH_ + pb;
    padA[oa]   = lrelu_(acc[0][o]);
    padA[oa+1] = lrelu_(acc[1][o]);
    padB[oa]   = lrelu_(acc[0][6+o]);
    padB[oa+1] = lrelu_(acc[1][6+o]);
  }
}

// ---------------- scpa: DUAL 3x3 conv on padded inputs, 4px/thread, aligned loads,
// LDS weight broadcast; k2 gate fused into B half (writes padded bufT + its borders).
// grid (16 rowtiles, 32 = half*16+g3), tb 256
__global__ __launch_bounds__(256) void k_conv3d(const float* __restrict__ padA,
                        const float* __restrict__ padB, const float* __restrict__ rpD,
                        const float* __restrict__ k2b,
                        float* __restrict__ outA, float* __restrict__ padT){
  __shared__ float lw[1536];
  int tid = threadIdx.x;
  int y = blockIdx.y;
  int half = y >> 4;
  int g3 = y & 15;
  const float* in = half ? padB : padA;
  const float* wg = rpD + (size_t)y*1536;
  for (int i=tid; i<384; i+=256)
    ((float4*)lw)[i] = ((const float4*)wg)[i];
  if (half && blockIdx.x == 0){
    for (int i=tid; i<1560; i+=256){
      int ch = i/520, rem = i%520;
      int row, col;
      if (rem < 132){ row = 0; col = rem; }
      else if (rem < 264){ row = 129; col = rem-132; }
      else { int rr = rem-264; row = 1 + (rr>>1); col = (rr&1) ? 129 : 0; }
      padT[(size_t)(g3*3+ch)*PCH_ + row*132 + col] = 0.f;
    }
  }
  __syncthreads();
  int orow = blockIdx.x*8 + (tid>>5);
  int cx = (tid&31)*4;
  float acc[4][3], gc[4][3];
  #pragma unroll
  for (int j=0;j<4;j++)
    #pragma unroll
    for (int o=0;o<3;o++){ acc[j][o]=0.f; gc[j][o]=0.f; }
  const float* ipb = in + (size_t)orow*132 + cx;
  for (int ic=0; ic<48; ic++){
    float w[32];
    #pragma unroll
    for (int q=0;q<8;q++) *(float4*)&w[q*4] = *(const float4*)&lw[ic*32+q*4];
    const float* ip = ipb + (size_t)ic*PCH_;
    float4 a0 = *(const float4*)(ip);       float2 b0 = *(const float2*)(ip+4);
    float4 a1 = *(const float4*)(ip+132);   float2 b1 = *(const float2*)(ip+136);
    float4 a2 = *(const float4*)(ip+264);   float2 b2 = *(const float2*)(ip+268);
    float f0[6] = {a0.x,a0.y,a0.z,a0.w,b0.x,b0.y};
    float f1[6] = {a1.x,a1.y,a1.z,a1.w,b1.x,b1.y};
    float f2[6] = {a2.x,a2.y,a2.z,a2.w,b2.x,b2.y};
    #pragma unroll
    for (int o=0;o<3;o++){
      #pragma unroll
      for (int j=0;j<4;j++){
        float a = acc[j][o];
        a = fmaf(f0[j],   w[o*9+0], a);
        a = fmaf(f0[j+1], w[o*9+1], a);
        a = fmaf(f0[j+2], w[o*9+2], a);
        a = fmaf(f1[j],   w[o*9+3], a);
        a = fmaf(f1[j+1], w[o*9+4], a);
        a = fmaf(f1[j+2], w[o*9+5], a);
        a = fmaf(f2[j],   w[o*9+6], a);
        a = fmaf(f2[j+1], w[o*9+7], a);
        a = fmaf(f2[j+2], w[o*9+8], a);
        acc[j][o] = a;
      }
    }
    if (half){
      #pragma unroll
      for (int j=0;j<4;j++){
        float cv = f1[j+1];
        gc[j][0] = fmaf(cv, w[27], gc[j][0]);
        gc[j][1] = fmaf(cv, w[28], gc[j][1]);
        gc[j][2] = fmaf(cv, w[29], gc[j][2]);
      }
    }
  }
  if (!half){
    int pb = orow*128 + cx;
    #pragma unroll
    for (int o=0;o<3;o++){
      float4 ov;
      ov.x = lrelu_(acc[0][o]); ov.y = lrelu_(acc[1][o]);
      ov.z = lrelu_(acc[2][o]); ov.w = lrelu_(acc[3][o]);
      *(float4*)&outA[(size_t)(g3*3+o)*HW + pb] = ov;
    }
  } else {
    size_t pb = (size_t)(orow+1)*132 + cx + 1;
    #pragma unroll
    for (int o=0;o<3;o++){
      float bb = k2b[g3*3+o];
      float* dst = padT + (size_t)(g3*3+o)*PCH_ + pb;
      #pragma unroll
      for (int j=0;j<4;j++)
        dst[j] = acc[j][o]*sigmoid_(gc[j][o]+bb);
    }
  }
}

// ---------------- scpa: single 3x3 conv (k4 + lrelu) on padded input, 4px/thread,
// 2 oc per group; grid (16 rowtiles, 24 g2), tb 256
__global__ __launch_bounds__(256) void k_conv3(const float* __restrict__ padT,
                        const float* __restrict__ rp3, float* __restrict__ out){
  __shared__ float lw[960];
  int tid = threadIdx.x;
  int g2 = blockIdx.y;
  const float* wg = rp3 + (size_t)g2*960;
  for (int i=tid; i<240; i+=256)
    ((float4*)lw)[i] = ((const float4*)wg)[i];
  __syncthreads();
  int orow = blockIdx.x*8 + (tid>>5);
  int cx = (tid&31)*4;
  float acc[4][2];
  #pragma unroll
  for (int j=0;j<4;j++){ acc[j][0]=0.f; acc[j][1]=0.f; }
  const float* ipb = padT + (size_t)orow*132 + cx;
  for (int ic=0; ic<48; ic++){
    float w[20];
    #pragma unroll
    for (int q=0;q<5;q++) *(float4*)&w[q*4] = *(const float4*)&lw[ic*20+q*4];
    const float* ip = ipb + (size_t)ic*PCH_;
    float4 a0 = *(const float4*)(ip);       float2 b0 = *(const float2*)(ip+4);
    float4 a1 = *(const float4*)(ip+132);   float2 b1 = *(const float2*)(ip+136);
    float4 a2 = *(const float4*)(ip+264);   float2 b2 = *(const float2*)(ip+268);
    float f0[6] = {a0.x,a0.y,a0.z,a0.w,b0.x,b0.y};
    float f1[6] = {a1.x,a1.y,a1.z,a1.w,b1.x,b1.y};
    float f2[6] = {a2.x,a2.y,a2.z,a2.w,b2.x,b2.y};
    #pragma unroll
    for (int o=0;o<2;o++){
      #pragma unroll
      for (int j=0;j<4;j++){
        float a = acc[j][o];
        a = fmaf(f0[j],   w[o*9+0], a);
        a = fmaf(f0[j+1], w[o*9+1], a);
        a = fmaf(f0[j+2], w[o*9+2], a);
        a = fmaf(f1[j],   w[o*9+3], a);
        a = fmaf(f1[j+1], w[o*9+4], a);
        a = fmaf(f1[j+2], w[o*9+5], a);
        a = fmaf(f2[j],   w[o*9+6], a);
        a = fmaf(f2[j+1], w[o*9+7], a);
        a = fmaf(f2[j+2], w[o*9+8], a);
        acc[j][o] = a;
      }
    }
  }
  int pb = orow*128 + cx;
  #pragma unroll
  for (int o=0;o<2;o++){
    float4 ov;
    ov.x = lrelu_(acc[0][o]); ov.y = lrelu_(acc[1][o]);
    ov.z = lrelu_(acc[2][o]); ov.w = lrelu_(acc[3][o]);
    *(float4*)&out[(size_t)(g2*2+o)*HW + pb] = ov;
  }
}

// ---------------- final 1x1 conv + both residuals; 2px/thread; LDS weights
__global__ __launch_bounds__(256) void k_c3(const float* __restrict__ ab,
                     const float* __restrict__ r3, const float* __restrict__ h2,
                     const float* __restrict__ xsum, float* __restrict__ out){
  __shared__ float lw[1152];
  int g = blockIdx.y;
  int tid = threadIdx.x;
  for (int i=tid; i<288; i+=256)
    ((float4*)lw)[i] = ((const float4*)(r3 + (size_t)g*1152))[i];
  __syncthreads();
  int p0 = (blockIdx.x*256 + tid)*2;
  float acc[2][12];
  #pragma unroll
  for (int i=0;i<2;i++)
    #pragma unroll
    for (int o=0;o<12;o++) acc[i][o]=0.f;
  for (int j=0;j<96;j++){
    float2 v = *(const float2*)&ab[(size_t)j*HW + p0];
    float4 w0 = *(const float4*)&lw[j*12];
    float4 w1 = *(const float4*)&lw[j*12+4];
    float4 w2 = *(const float4*)&lw[j*12+8];
    acc[0][0] = fmaf(v.x, w0.x, acc[0][0]); acc[1][0] = fmaf(v.y, w0.x, acc[1][0]);
    acc[0][1] = fmaf(v.x, w0.y, acc[0][1]); acc[1][1] = fmaf(v.y, w0.y, acc[1][1]);
    acc[0][2] = fmaf(v.x, w0.z, acc[0][2]); acc[1][2] = fmaf(v.y, w0.z, acc[1][2]);
    acc[0][3] = fmaf(v.x, w0.w, acc[0][3]); acc[1][3] = fmaf(v.y, w0.w, acc[1][3]);
    acc[0][4] = fmaf(v.x, w1.x, acc[0][4]); acc[1][4] = fmaf(v.y, w1.x, acc[1][4]);
    acc[0][5] = fmaf(v.x, w1.y, acc[0][5]); acc[1][5] = fmaf(v.y, w1.y, acc[1][5]);
    acc[0][6] = fmaf(v.x, w1.z, acc[0][6]); acc[1][6] = fmaf(v.y, w1.z, acc[1][6]);
    acc[0][7] = fmaf(v.x, w1.w, acc[0][7]); acc[1][7] = fmaf(v.y, w1.w, acc[1][7]);
    acc[0][8] = fmaf(v.x, w2.x, acc[0][8]); acc[1][8] = fmaf(v.y, w2.x, acc[1][8]);
    acc[0][9] = fmaf(v.x, w2.y, acc[0][9]); acc[1][9] = fmaf(v.y, w2.y, acc[1][9]);
    acc[0][10]= fmaf(v.x, w2.z, acc[0][10]); acc[1][10]= fmaf(v.y, w2.z, acc[1][10]);
    acc[0][11]= fmaf(v.x, w2.w, acc[0][11]); acc[1][11]= fmaf(v.y, w2.w, acc[1][11]);
  }
  #pragma unroll
  for (int o=0;o<12;o++){
    size_t oi = (size_t)(g*12+o)*HW + p0;
    float2 hv = *(const float2*)&h2[oi];
    float2 sv = *(const float2*)&xsum[oi];
    float2 ov;
    ov.x = acc[0][o] + hv.x + sv.x;
    ov.y = acc[1][o] + hv.y + sv.y;
    *(float2*)&out[oi] = ov;
  }
}

extern "C" void kernel_launch(void* const* d_in, const int* in_sizes, int n_in,
                              void* d_out, int out_size, void* d_ws, size_t ws_size,
                              hipStream_t stream){
  (void)in_sizes; (void)n_in; (void)out_size; (void)ws_size;
  const float* x    = (const float*)d_in[0];
  const float* bn1g = (const float*)d_in[1];
  const float* bn1b = (const float*)d_in[2];
  const float* bn1m = (const float*)d_in[3];
  const float* bn1v = (const float*)d_in[4];
  const float* caw1 = (const float*)d_in[5];
  const float* caw2 = (const float*)d_in[6];
  const float* peW  = (const float*)d_in[7];
  const float* peb  = (const float*)d_in[8];
  const float* puW  = (const float*)d_in[9];
  const float* pub  = (const float*)d_in[10];
  const float* lng  = (const float*)d_in[11];
  const float* lnb  = (const float*)d_in[12];
  const float* inW  = (const float*)d_in[13];
  const float* convw= (const float*)d_in[14];
  const float* convb= (const float*)d_in[15];
  const float* xprojw=(const float*)d_in[16];
  const float* dtw  = (const float*)d_in[17];
  const float* dtb  = (const float*)d_in[18];
  const float* Alog = (const float*)d_in[19];
  const float* Dsk  = (const float*)d_in[20];
  const float* ong  = (const float*)d_in[21];
  const float* onb  = (const float*)d_in[22];
  const float* outW = (const float*)d_in[23];
  const float* mw   = (const float*)d_in[24];
  const float* bn2g = (const float*)d_in[25];
  const float* bn2b = (const float*)d_in[26];
  const float* bn2m = (const float*)d_in[27];
  const float* bn2v = (const float*)d_in[28];
  const float* c1a  = (const float*)d_in[29];
  const float* c1b  = (const float*)d_in[30];
  const float* k1w  = (const float*)d_in[31];
  const float* k2w  = (const float*)d_in[32];
  const float* k2b  = (const float*)d_in[33];
  const float* k3w  = (const float*)d_in[34];
  const float* k4w  = (const float*)d_in[35];
  const float* c3w  = (const float*)d_in[36];
  float* out = (float*)d_out;

  float* ws = (float*)d_ws;
  size_t off = 0;
  auto alloc = [&](size_t n){ float* p = ws + off; off += n; return p; };
  float* peWT  = alloc((size_t)1536*192);
  float* puWT  = alloc((size_t)192*1536);
  float* inWT  = alloc((size_t)8*192*768);
  float* outWT = alloc((size_t)8*384*192);
  float* bufH  = alloc((size_t)96*HW);
  float* stats = alloc(256);
  float* x2a   = alloc((size_t)1024*192);
  float* x2b   = alloc((size_t)1024*192);
  float* bufXZ = alloc((size_t)1024*768);
  float* bufXCS= alloc((size_t)384*1024);
  float* bufXST= alloc((size_t)4*1024*384);  // xst0|xst1 (half used); later ab (96ch)
  float* xdblP = alloc((size_t)12*44*1024);
  float* dts   = alloc((size_t)4*1024*384);
  float* bc    = alloc((size_t)4*1024*32);
  float* yst   = alloc((size_t)4*1024*384);
  float* bufY  = alloc((size_t)1024*384);
  float* xsum  = alloc((size_t)96*HW);
  float* h2    = alloc((size_t)96*HW);
  float* ehB   = alloc((size_t)2*K_*NCH_*DI_*NS_);  // packed (E,H) float2
  float* wpk   = alloc((size_t)K_*NCH_*DI_*NS_); // repacked weights (393216 floats)
  float* suB   = alloc(1024);
  float* sqB   = alloc(1024);
  float* padA  = alloc((size_t)48*PCH_);
  float* padB  = alloc((size_t)48*PCH_);
  float* padT  = alloc((size_t)48*PCH_);
  float* xst0  = bufXST;
  float* xst1  = bufXST + (size_t)L_*DI_;
  float2* eh   = (float2*)ehB;

  float* rpD  = wpk;                // 49152
  float* rp3  = wpk + 49152;        // 23040
  float* r1w  = wpk + 72192;        // 9216
  float* r3w  = wpk + 81408;        // 9216
  float* dtwT = wpk + 90624;        // 147456

  dim3 tb(32,8);
  k_transAll<<<3234, tb, 0, stream>>>(peW, peWT, puW, puWT, inW, inWT, outW, outWT,
                                      k1w, k3w, k2w, k4w, c1a, c1b, c3w, dtw,
                                      rpD, rp3, r1w, r3w, dtwT);

  k_bn1<<<96,256,0,stream>>>(x, bn1g, bn1b, bn1m, bn1v, bufH, stats, suB, sqB);
  k_gemmPE<<<dim3(32,6),256,0,stream>>>(bufH, peWT, peb, x2a, suB, sqB);

  float* cur = x2a; float* nxt = x2b;
  for (int b=0;b<8;b++){
    k_gemm32ln<<<dim3(32,12),256,0,stream>>>(cur, inWT+(size_t)b*192*768,
                        lng+(size_t)b*192, lnb+(size_t)b*192, suB, sqB, bufXZ, 192, 768);
    k_dwxst<<<dim3(32,12),tb,0,stream>>>(bufXZ, convw+(size_t)b*384*9,
                        convb+(size_t)b*384, bufXCS, xst0, xst1);
    k_xdblP<<<dim3(4,11,12),256,0,stream>>>(bufXCS, xprojw+(size_t)b*4*44*384, xdblP);
    k_dtbc<<<dim3(256,4),384,0,stream>>>(xdblP, dtwT+(size_t)b*18432, dtb+(size_t)b*4*384, dts, bc);
    const float* Ab = Alog + (size_t)b*4*384*16;
    {
      const float* a0 = xst0; const float* a1 = xst1;
      const float* a2 = dts;  const float* a3 = bc;
      void* args[] = { (void*)&a0, (void*)&a1, (void*)&a2, (void*)&a3,
                       (void*)&Ab, (void*)&eh, (void*)&yst };
      hipLaunchCooperativeKernel((void*)k_scanAC, dim3(NCH_,DI_/16,4), dim3(256),
                                 args, 0, stream);
    }
    k_merge<<<1024,384,0,stream>>>(yst, xst0, xst1, Dsk+(size_t)b*4*384, mw+(size_t)b*4,
                                   ong+(size_t)b*384, onb+(size_t)b*384, bufXZ, bufY, suB, sqB);
    k_gemm32s<<<dim3(32,6),256,0,stream>>>(bufY, outWT+(size_t)b*384*192, cur, nxt, suB, sqB, 384, 192);
    float* t = cur; cur = nxt; nxt = t;
  }

  k_gemmPUs<<<dim3(32,24),256,0,stream>>>(cur, puWT, pub, x, bufH, stats, caw1, caw2,
                                          bn2g, bn2b, bn2m, bn2v, xsum, h2);

  float* ab = bufXST;
  k_1x1ab<<<dim3(32,8),256,0,stream>>>(h2, r1w, padA, padB);
  k_conv3d<<<dim3(16,32),256,0,stream>>>(padA, padB, rpD, k2b, ab, padT);
  k_conv3<<<dim3(16,24),256,0,stream>>>(padT, rp3, ab+(size_t)48*HW);
  k_c3<<<dim3(32,8),256,0,stream>>>(ab, r3w, h2, xsum, out);
}

// Round 12
// 955.210 us; speedup vs baseline: 1.7399x; 1.7399x over previous
//
#include <hip/hip_runtime.h>
#include <math.h>

#define HW 16384
constexpr int C_ = 96;
constexpr int E_ = 192, DI_ = 384, NS_ = 16, R_ = 12, K_ = 4, NBLK_ = 8, GW_ = 48;
constexpr int L_ = 1024, CXP_ = 44; // R + 2*NS
constexpr int TC_ = 64;             // scan chunk length
constexpr int NCH_ = L_ / TC_;      // 16 chunks
constexpr int PCH_ = 130*132;       // padded conv channel size

__device__ __forceinline__ float lrelu_(float x){ return x >= 0.f ? x : 0.2f*x; }
__device__ __forceinline__ float sigmoid_(float x){ return 1.f/(1.f+expf(-x)); }
__device__ __forceinline__ float silu_(float x){ return x/(1.f+expf(-x)); }
__device__ __forceinline__ float softplus_(float x){ return fmaxf(x,0.f)+log1pf(expf(-fabsf(x))); }

// 16-lane row sum via DPP row_shr adds (VALU only, no LDS). Lane 15 of each
// 16-lane row ends with the full row sum. bound_ctrl=0-fill keeps rows independent.
__device__ __forceinline__ float rowsum16_(float p){
  int q;
  q = __builtin_amdgcn_update_dpp(0, __float_as_int(p), 0x111, 0xf, 0xf, true); p += __int_as_float(q);
  q = __builtin_amdgcn_update_dpp(0, __float_as_int(p), 0x112, 0xf, 0xf, true); p += __int_as_float(q);
  q = __builtin_amdgcn_update_dpp(0, __float_as_int(p), 0x114, 0xf, 0xf, true); p += __int_as_float(q);
  q = __builtin_amdgcn_update_dpp(0, __float_as_int(p), 0x118, 0xf, 0xf, true); p += __int_as_float(q);
  return p;
}

// 64-lane wave sum via DPP (row_shr + row_bcast); lane 63 holds the full sum.
__device__ __forceinline__ float wsum64_(float v){
  int q;
  q = __builtin_amdgcn_update_dpp(0, __float_as_int(v), 0x111, 0xf, 0xf, true); v += __int_as_float(q);
  q = __builtin_amdgcn_update_dpp(0, __float_as_int(v), 0x112, 0xf, 0xf, true); v += __int_as_float(q);
  q = __builtin_amdgcn_update_dpp(0, __float_as_int(v), 0x114, 0xf, 0xf, true); v += __int_as_float(q);
  q = __builtin_amdgcn_update_dpp(0, __float_as_int(v), 0x118, 0xf, 0xf, true); v += __int_as_float(q);
  q = __builtin_amdgcn_update_dpp(0, __float_as_int(v), 0x142, 0xa, 0xf, true); v += __int_as_float(q);
  q = __builtin_amdgcn_update_dpp(0, __float_as_int(v), 0x143, 0xc, 0xf, true); v += __int_as_float(q);
  return v;
}

// 64-lane wave max via DPP; lane 63 holds the full max (old=self keeps identity).
__device__ __forceinline__ float wmax64_(float v){
  int q;
  q = __builtin_amdgcn_update_dpp(__float_as_int(v), __float_as_int(v), 0x111, 0xf, 0xf, false); v = fmaxf(v, __int_as_float(q));
  q = __builtin_amdgcn_update_dpp(__float_as_int(v), __float_as_int(v), 0x112, 0xf, 0xf, false); v = fmaxf(v, __int_as_float(q));
  q = __builtin_amdgcn_update_dpp(__float_as_int(v), __float_as_int(v), 0x114, 0xf, 0xf, false); v = fmaxf(v, __int_as_float(q));
  q = __builtin_amdgcn_update_dpp(__float_as_int(v), __float_as_int(v), 0x118, 0xf, 0xf, false); v = fmaxf(v, __int_as_float(q));
  q = __builtin_amdgcn_update_dpp(__float_as_int(v), __float_as_int(v), 0x142, 0xa, 0xf, false); v = fmaxf(v, __int_as_float(q));
  q = __builtin_amdgcn_update_dpp(__float_as_int(v), __float_as_int(v), 0x143, 0xc, 0xf, false); v = fmaxf(v, __int_as_float(q));
  return v;
}

// ---------------- all 4 weight transposes + SCPA weight repack + dtw transpose
__global__ void k_transAll(const float* __restrict__ peW, float* __restrict__ peWT,
                           const float* __restrict__ puW, float* __restrict__ puWT,
                           const float* __restrict__ inW, float* __restrict__ inWT,
                           const float* __restrict__ outW, float* __restrict__ outWT,
                           const float* __restrict__ k1w, const float* __restrict__ k3w,
                           const float* __restrict__ k2w, const float* __restrict__ k4w,
                           const float* __restrict__ c1a, const float* __restrict__ c1b,
                           const float* __restrict__ c3w, const float* __restrict__ dtw,
                           float* __restrict__ rpD, float* __restrict__ rp3,
                           float* __restrict__ r1, float* __restrict__ r3,
                           float* __restrict__ dtwT){
  __shared__ float t[32][33];
  int id = blockIdx.x;
  if (id >= 2304){
    int idx = (id-2304)*256 + threadIdx.y*32 + threadIdx.x;
    if (idx < 49152){
      int y = idx/1536, r = idx%1536, ic = r>>5, j = r&31;
      float v = 0.f;
      if (y < 16){
        if (j < 27) v = k1w[((size_t)((y*3 + j/9)*48 + ic))*9 + j%9];
      } else {
        int g = y-16;
        if (j < 27) v = k3w[((size_t)((g*3 + j/9)*48 + ic))*9 + j%9];
        else if (j < 30) v = k2w[(size_t)(g*3 + (j-27))*48 + ic];
      }
      rpD[idx] = v;
    } else if (idx < 72192){
      int tt = idx - 49152;
      int y = tt/960, rem = tt%960, ic = rem/20, j = rem%20;
      float v = 0.f;
      if (j < 18) v = k4w[((size_t)((y*2 + j/9)*48 + ic))*9 + j%9];
      rp3[tt] = v;
    } else if (idx < 81408){
      int tt = idx - 72192;
      int g = tt/1152, r = tt%1152, ic = r/12, j = r%12;
      r1[tt] = (j<6) ? c1a[(size_t)(g*6+j)*96+ic] : c1b[(size_t)(g*6+j-6)*96+ic];
    } else if (idx < 90624){
      int tt = idx - 81408;
      int g = tt/1152, r = tt%1152, ic = r/12, j = r%12;
      r3[tt] = c3w[(size_t)(g*12+j)*96+ic];
    } else if (idx < 238080){
      int tt = idx - 90624;
      int b = tt/18432, rem = tt%18432;
      int k = rem/4608, rem2 = rem%4608, r = rem2/384, d = rem2%384;
      dtwT[tt] = dtw[(((size_t)(b*4 + k)*384 + d))*12 + r];
    }
    return;
  }
  const float* in; float* out; int rows, cols, bx, by;
  if (id < 288){ in=peW; out=peWT; rows=192; cols=1536; bx=id%48; by=id/48; }
  else if (id < 576){ int r=id-288; in=puW; out=puWT; rows=1536; cols=192; bx=r%6; by=r/6; }
  else if (id < 1728){ int r=id-576; int z=r/144; int q=r%144;
    in=inW+(size_t)z*768*192; out=inWT+(size_t)z*768*192; rows=768; cols=192; bx=q%6; by=q/6; }
  else { int r=id-1728; int z=r/72; int q=r%72;
    in=outW+(size_t)z*192*384; out=outWT+(size_t)z*192*384; rows=192; cols=384; bx=q%12; by=q/12; }
  int r0=by*32, c0=bx*32, tx=threadIdx.x, ty=threadIdx.y;
  for (int i=0;i<32;i+=8){
    int r=r0+ty+i, c=c0+tx;
    if (r<rows && c<cols) t[ty+i][tx]=in[(size_t)r*cols+c];
  }
  __syncthreads();
  for (int i=0;i<32;i+=8){
    int c=c0+ty+i, r=r0+tx;
    if (r<rows && c<cols) out[(size_t)c*rows+r]=t[tx][ty+i];
  }
}

// ---------------- bn1 + per-channel mean/max stats; also zeroes LN-sum buffers
__global__ void k_bn1(const float* __restrict__ x, const float* g, const float* b,
                      const float* m, const float* v,
                      float* __restrict__ h, float* __restrict__ stats,
                      float* __restrict__ su, float* __restrict__ sq){
  int c = blockIdx.x, tid = threadIdx.x;
  int gid = c*256 + tid;
  if (gid < 1024){ su[gid] = 0.f; sq[gid] = 0.f; }
  float sc = g[c]*rsqrtf(v[c]+1e-5f), sh = b[c]-m[c]*sc;
  const float* xc = x + (size_t)c*HW;
  float* hc = h + (size_t)c*HW;
  float s = 0.f, mx = -1e30f;
  for (int i=tid;i<HW;i+=256){
    float val = fmaf(xc[i], sc, sh);
    hc[i] = val; s += val; mx = fmaxf(mx, val);
  }
  s = wsum64_(s); mx = wmax64_(mx);
  __shared__ float ss[4], sm[4];
  int wid = tid>>6, lane = tid&63;
  if (lane==63){ ss[wid]=s; sm[wid]=mx; }
  __syncthreads();
  if (!tid){
    stats[c] = (ss[0]+ss[1]+ss[2]+ss[3])*(1.f/HW);
    stats[96+c] = fmaxf(fmaxf(sm[0],sm[1]),fmaxf(sm[2],sm[3]));
  }
}

// ---------------- pe GEMM: A = patchified bufH (fused addressing), + bias + LN-stat atomics
__global__ __launch_bounds__(256) void k_gemmPE(const float* __restrict__ hsrc,
                      const float* __restrict__ wt, const float* __restrict__ bias,
                      float* __restrict__ out, float* __restrict__ su, float* __restrict__ sq){
  const int K = 1536, N = 192;
  __shared__ float As[32][34];
  __shared__ float Bs[32][32];
  int tid = threadIdx.x;
  int m0 = blockIdx.x*32, n0 = blockIdx.y*32;
  int tx = tid&15, ty = tid>>4;
  int arow = tid>>3, akq = tid&7;
  int brow = tid>>3, bn4 = tid&7;
  int m = m0+arow;
  int base2 = (m>>5)*512 + (m&31)*4;
  auto aload = [&](int kk)->float4 {
    int c = kk>>4, i2 = (kk>>2)&3;
    return *(const float4*)&hsrc[((size_t)c<<14) + (size_t)(i2*128 + base2)];
  };
  float4 aR = aload(akq*4);
  float4 bR = *(const float4*)&wt[(size_t)brow*N + n0 + bn4*4];
  float acc[2][2] = {{0}};
  for (int k0=0; k0<K; k0+=32){
    __syncthreads();
    As[akq*4+0][arow]=aR.x; As[akq*4+1][arow]=aR.y;
    As[akq*4+2][arow]=aR.z; As[akq*4+3][arow]=aR.w;
    *(float4*)&Bs[brow][bn4*4] = bR;
    __syncthreads();
    if (k0+32 < K){
      aR = aload(k0+32+akq*4);
      bR = *(const float4*)&wt[(size_t)(k0+32+brow)*N + n0 + bn4*4];
    }
    #pragma unroll
    for (int kk=0; kk<32; kk++){
      float2 av = *(const float2*)&As[kk][ty*2];
      float2 bv = *(const float2*)&Bs[kk][tx*2];
      acc[0][0] = fmaf(av.x, bv.x, acc[0][0]);
      acc[0][1] = fmaf(av.x, bv.y, acc[0][1]);
      acc[1][0] = fmaf(av.y, bv.x, acc[1][0]);
      acc[1][1] = fmaf(av.y, bv.y, acc[1][1]);
    }
  }
  float2 bq = *(const float2*)&bias[n0+tx*2];
  float sl[2], ql[2];
  #pragma unroll
  for (int i=0;i<2;i++){
    size_t o = (size_t)(m0+ty*2+i)*N + n0 + tx*2;
    float2 ov; ov.x = acc[i][0]+bq.x; ov.y = acc[i][1]+bq.y;
    *(float2*)&out[o] = ov;
    sl[i] = ov.x+ov.y; ql[i] = ov.x*ov.x+ov.y*ov.y;
  }
  sl[0] = rowsum16_(sl[0]); ql[0] = rowsum16_(ql[0]);
  sl[1] = rowsum16_(sl[1]); ql[1] = rowsum16_(ql[1]);
  if (tx==15){
    atomicAdd(&su[m0+ty*2],   sl[0]); atomicAdd(&sq[m0+ty*2],   ql[0]);
    atomicAdd(&su[m0+ty*2+1], sl[1]); atomicAdd(&sq[m0+ty*2+1], ql[1]);
  }
}

// ---------------- gemm32 + residual + LN-stat atomics (outproj); grid (M/32,N/32)
__global__ __launch_bounds__(256) void k_gemm32s(const float* __restrict__ act,
                      const float* __restrict__ wt, const float* __restrict__ res,
                      float* __restrict__ out, float* __restrict__ su, float* __restrict__ sq,
                      int K, int N){
  __shared__ float As[32][34];
  __shared__ float Bs[32][32];
  int tid = threadIdx.x;
  int m0 = blockIdx.x*32, n0 = blockIdx.y*32;
  int tx = tid&15, ty = tid>>4;
  int arow = tid>>3, akq = tid&7;
  int brow = tid>>3, bn4 = tid&7;
  float4 aR = *(const float4*)&act[(size_t)(m0+arow)*K + akq*4];
  float4 bR = *(const float4*)&wt [(size_t)brow*N + n0 + bn4*4];
  float acc[2][2] = {{0}};
  for (int k0=0; k0<K; k0+=32){
    __syncthreads();
    As[akq*4+0][arow]=aR.x; As[akq*4+1][arow]=aR.y;
    As[akq*4+2][arow]=aR.z; As[akq*4+3][arow]=aR.w;
    *(float4*)&Bs[brow][bn4*4] = bR;
    __syncthreads();
    if (k0+32 < K){
      aR = *(const float4*)&act[(size_t)(m0+arow)*K + k0+32 + akq*4];
      bR = *(const float4*)&wt [(size_t)(k0+32+brow)*N + n0 + bn4*4];
    }
    #pragma unroll
    for (int kk=0; kk<32; kk++){
      float2 av = *(const float2*)&As[kk][ty*2];
      float2 bv = *(const float2*)&Bs[kk][tx*2];
      acc[0][0] = fmaf(av.x, bv.x, acc[0][0]);
      acc[0][1] = fmaf(av.x, bv.y, acc[0][1]);
      acc[1][0] = fmaf(av.y, bv.x, acc[1][0]);
      acc[1][1] = fmaf(av.y, bv.y, acc[1][1]);
    }
  }
  float sl[2], ql[2];
  #pragma unroll
  for (int i=0;i<2;i++){
    size_t o = (size_t)(m0+ty*2+i)*N + n0 + tx*2;
    float2 r = *(const float2*)&res[o];
    float2 ov; ov.x = acc[i][0]+r.x; ov.y = acc[i][1]+r.y;
    *(float2*)&out[o] = ov;
    sl[i] = ov.x+ov.y; ql[i] = ov.x*ov.x+ov.y*ov.y;
  }
  sl[0] = rowsum16_(sl[0]); ql[0] = rowsum16_(ql[0]);
  sl[1] = rowsum16_(sl[1]); ql[1] = rowsum16_(ql[1]);
  if (tx==15){
    atomicAdd(&su[m0+ty*2],   sl[0]); atomicAdd(&sq[m0+ty*2],   ql[0]);
    atomicAdd(&su[m0+ty*2+1], sl[1]); atomicAdd(&sq[m0+ty*2+1], ql[1]);
  }
}

// ---------------- pu GEMM (32x64 tile, 2x4 acc) + bias + residual-sum + attn + bn2
// grid (32, 24), tb 256
__global__ __launch_bounds__(256) void k_gemmPUs(const float* __restrict__ act,
                      const float* __restrict__ wt, const float* __restrict__ bias,
                      const float* __restrict__ x, const float* __restrict__ bufH,
                      const float* __restrict__ stats, const float* __restrict__ caw1,
                      const float* __restrict__ caw2,
                      const float* __restrict__ g2, const float* __restrict__ b2,
                      const float* __restrict__ m2, const float* __restrict__ v2,
                      float* __restrict__ xsum, float* __restrict__ h2){
  const int K = 192, N = 1536;
  __shared__ float As[32][34];
  __shared__ float Bs[32][68];
  __shared__ float hid_[12];
  int tid = threadIdx.x;
  if (tid < 12){
    int j = tid%6, which = tid/6;
    const float* vv = stats + which*96;
    float a = 0.f;
    for (int c=0;c<96;c++) a += vv[c]*caw1[j*96+c];
    hid_[tid] = fmaxf(a, 0.f);
  }
  int m0 = blockIdx.x*32, n0 = blockIdx.y*64;
  int tx = tid&15, ty = tid>>4;
  int arow = tid>>3, akq = tid&7;
  int brow = tid>>4, bnq = tid&15;
  float4 aR = *(const float4*)&act[(size_t)(m0+arow)*K + akq*4];
  float4 b0 = *(const float4*)&wt[(size_t)brow*N + n0 + bnq*4];
  float4 b1 = *(const float4*)&wt[(size_t)(brow+16)*N + n0 + bnq*4];
  float acc[2][4] = {{0}};
  for (int k0=0; k0<K; k0+=32){
    __syncthreads();
    As[akq*4+0][arow]=aR.x; As[akq*4+1][arow]=aR.y;
    As[akq*4+2][arow]=aR.z; As[akq*4+3][arow]=aR.w;
    *(float4*)&Bs[brow][bnq*4] = b0;
    *(float4*)&Bs[brow+16][bnq*4] = b1;
    __syncthreads();
    if (k0+32 < K){
      aR = *(const float4*)&act[(size_t)(m0+arow)*K + k0+32 + akq*4];
      b0 = *(const float4*)&wt[(size_t)(k0+32+brow)*N + n0 + bnq*4];
      b1 = *(const float4*)&wt[(size_t)(k0+48+brow)*N + n0 + bnq*4];
    }
    #pragma unroll
    for (int kk=0; kk<32; kk++){
      float2 av = *(const float2*)&As[kk][ty*2];
      float4 bv = *(const float4*)&Bs[kk][tx*4];
      acc[0][0] = fmaf(av.x, bv.x, acc[0][0]);
      acc[0][1] = fmaf(av.x, bv.y, acc[0][1]);
      acc[0][2] = fmaf(av.x, bv.z, acc[0][2]);
      acc[0][3] = fmaf(av.x, bv.w, acc[0][3]);
      acc[1][0] = fmaf(av.y, bv.x, acc[1][0]);
      acc[1][1] = fmaf(av.y, bv.y, acc[1][1]);
      acc[1][2] = fmaf(av.y, bv.z, acc[1][2]);
      acc[1][3] = fmaf(av.y, bv.w, acc[1][3]);
    }
  }
  int n = n0 + tx*4;
  float4 bq = *(const float4*)&bias[n];
  int c = n>>4, i2 = (n>>2)&3;
  float at;
  {
    float a = 0.f;
    #pragma unroll
    for (int jj=0;jj<6;jj++) a += (hid_[jj]+hid_[6+jj])*caw2[c*6+jj];
    at = sigmoid_(a);
  }
  float sc2 = g2[c]*rsqrtf(v2[c]+1e-5f);
  float sh2 = b2[c]-m2[c]*sc2;
  #pragma unroll
  for (int i=0;i<2;i++){
    int m = m0+ty*2+i;
    size_t o = ((size_t)c<<14) + (size_t)((m>>5)*4+i2)*128 + (m&31)*4;
    float4 xv = *(const float4*)&x[o];
    float4 hv = *(const float4*)&bufH[o];
    float4 sv;
    sv.x = xv.x + hv.x*at + acc[i][0]+bq.x;
    sv.y = xv.y + hv.y*at + acc[i][1]+bq.y;
    sv.z = xv.z + hv.z*at + acc[i][2]+bq.z;
    sv.w = xv.w + hv.w*at + acc[i][3]+bq.w;
    *(float4*)&xsum[o] = sv;
    float4 h2v;
    h2v.x = fmaf(sv.x, sc2, sh2);
    h2v.y = fmaf(sv.y, sc2, sh2);
    h2v.z = fmaf(sv.z, sc2, sh2);
    h2v.w = fmaf(sv.w, sc2, sh2);
    *(float4*)&h2[o] = h2v;
  }
}

// ---------------- gemm (32x64 tile, 2x4 acc) with layernorm fused on A; grid (32, N/64)
__global__ __launch_bounds__(256) void k_gemm32ln(const float* __restrict__ act,
                      const float* __restrict__ wt, const float* __restrict__ lg,
                      const float* __restrict__ lb, const float* __restrict__ su,
                      const float* __restrict__ sq, float* __restrict__ out,
                      int K, int N){
  __shared__ float As[32][34];
  __shared__ float Bs[32][68];
  int tid = threadIdx.x;
  int m0 = blockIdx.x*32, n0 = blockIdx.y*64;
  int tx = tid&15, ty = tid>>4;
  int arow = tid>>3, akq = tid&7;
  int brow = tid>>4, bnq = tid&15;
  float m = su[m0+arow]*(1.f/192.f);
  float r = rsqrtf(sq[m0+arow]*(1.f/192.f) - m*m + 1e-5f);
  float4 aR = *(const float4*)&act[(size_t)(m0+arow)*K + akq*4];
  float4 gR = *(const float4*)&lg[akq*4];
  float4 hR = *(const float4*)&lb[akq*4];
  float4 b0 = *(const float4*)&wt[(size_t)brow*N + n0 + bnq*4];
  float4 b1 = *(const float4*)&wt[(size_t)(brow+16)*N + n0 + bnq*4];
  float acc[2][4] = {{0}};
  for (int k0=0; k0<K; k0+=32){
    __syncthreads();
    As[akq*4+0][arow] = (aR.x-m)*r*gR.x + hR.x;
    As[akq*4+1][arow] = (aR.y-m)*r*gR.y + hR.y;
    As[akq*4+2][arow] = (aR.z-m)*r*gR.z + hR.z;
    As[akq*4+3][arow] = (aR.w-m)*r*gR.w + hR.w;
    *(float4*)&Bs[brow][bnq*4] = b0;
    *(float4*)&Bs[brow+16][bnq*4] = b1;
    __syncthreads();
    if (k0+32 < K){
      aR = *(const float4*)&act[(size_t)(m0+arow)*K + k0+32 + akq*4];
      gR = *(const float4*)&lg[k0+32+akq*4];
      hR = *(const float4*)&lb[k0+32+akq*4];
      b0 = *(const float4*)&wt[(size_t)(k0+32+brow)*N + n0 + bnq*4];
      b1 = *(const float4*)&wt[(size_t)(k0+48+brow)*N + n0 + bnq*4];
    }
    #pragma unroll
    for (int kk=0; kk<32; kk++){
      float2 av = *(const float2*)&As[kk][ty*2];
      float4 bv = *(const float4*)&Bs[kk][tx*4];
      acc[0][0] = fmaf(av.x, bv.x, acc[0][0]);
      acc[0][1] = fmaf(av.x, bv.y, acc[0][1]);
      acc[0][2] = fmaf(av.x, bv.z, acc[0][2]);
      acc[0][3] = fmaf(av.x, bv.w, acc[0][3]);
      acc[1][0] = fmaf(av.y, bv.x, acc[1][0]);
      acc[1][1] = fmaf(av.y, bv.y, acc[1][1]);
      acc[1][2] = fmaf(av.y, bv.z, acc[1][2]);
      acc[1][3] = fmaf(av.y, bv.w, acc[1][3]);
    }
  }
  #pragma unroll
  for (int i=0;i<2;i++){
    float4 ov;
    ov.x = acc[i][0]; ov.y = acc[i][1]; ov.z = acc[i][2]; ov.w = acc[i][3];
    *(float4*)&out[(size_t)(m0+ty*2+i)*N + n0 + tx*4] = ov;
  }
}

// ---------------- fused depthwise conv + silu + 2-layout xst build; grid (32 h0, 12 d0), tb (32,8)
__global__ __launch_bounds__(256) void k_dwxst(const float* __restrict__ xz,
                        const float* __restrict__ w, const float* __restrict__ bias,
                        float* __restrict__ xcs, float* __restrict__ xst0,
                        float* __restrict__ xst1){
  __shared__ float ld[96][33];
  __shared__ float t[32][33];
  int h0 = blockIdx.x;
  int d0 = blockIdx.y*32;
  int tx = threadIdx.x, ty = threadIdx.y;
  #pragma unroll
  for (int i=0;i<12;i++){
    int ll = i*8 + ty;
    int h = h0 - 1 + (ll>>5);
    int wv = ll & 31;
    float v = 0.f;
    if ((unsigned)h < 32u) v = xz[(size_t)(h*32+wv)*768 + d0 + tx];
    ld[ll][tx] = v;
  }
  __syncthreads();
  #pragma unroll
  for (int i=0;i<4;i++){
    int dl = ty + 8*i;
    int d = d0 + dl;
    float acc = bias[d];
    const float* wp = w + d*9;
    #pragma unroll
    for (int di=0;di<3;di++){
      #pragma unroll
      for (int dj=0;dj<3;dj++){
        int wq = tx + dj - 1;
        if ((unsigned)wq < 32u)
          acc = fmaf(ld[di*32 + wq][dl], wp[di*3+dj], acc);
      }
    }
    float val = silu_(acc);
    xcs[(size_t)d*L_ + h0*32 + tx] = val;
    t[dl][tx] = val;
  }
  __syncthreads();
  int d = d0 + tx;
  #pragma unroll
  for (int i=0;i<4;i++){
    int wq = ty + 8*i;
    int l = h0*32 + wq;
    float val = t[tx][wq];
    int t1 = wq*32 + h0;
    xst0[(size_t)l*DI_ + d] = val;
    xst1[(size_t)t1*DI_ + d] = val;
  }
}

// ---------------- x_dbl partial (split-K over d, 3 x 128): grid (4, 11, 12)
__global__ __launch_bounds__(256) void k_xdblP(const float* __restrict__ xcs,
                       const float* __restrict__ xw, float* __restrict__ xdblP){
  __shared__ float lw[512];
  int kz = blockIdx.z;
  int k = kz & 3, sp = kz >> 2;
  int c0 = blockIdx.y*4;
  int tid = threadIdx.x;
  for (int i=tid; i<512; i+=256){
    int d = i>>2, c = i&3;
    lw[i] = xw[((size_t)k*CXP_ + c0 + c)*DI_ + sp*128 + d];
  }
  __syncthreads();
  int s = blockIdx.x*256 + tid;
  int Ts = ((s&31)<<5) | (s>>5);
  int lwi;
  if (k==0) lwi = s;
  else if (k==1) lwi = Ts;
  else if (k==2) lwi = 1023-s;
  else lwi = 1023-Ts;
  const float* src = xcs + s + (size_t)sp*128*L_;
  float a0=0,a1=0,a2=0,a3=0;
  for (int d=0; d<128; d++){
    float v = src[(size_t)d*L_];
    float4 w4 = *(const float4*)&lw[d*4];
    a0 = fmaf(v, w4.x, a0);
    a1 = fmaf(v, w4.y, a1);
    a2 = fmaf(v, w4.z, a2);
    a3 = fmaf(v, w4.w, a3);
  }
  size_t base = (((size_t)sp*4 + k)*CXP_ + c0)*L_ + lwi;
  xdblP[base]       = a0;
  xdblP[base+L_]    = a1;
  xdblP[base+2*L_]  = a2;
  xdblP[base+3*L_]  = a3;
}

// ---------------- combine partials + dt proj + softplus -> dts_t; repack B,C -> bc
// 4 l per block; psums staged in LDS; coalesced dtwT weights. grid (256, 4), tb 384
__global__ __launch_bounds__(384) void k_dtbc(const float* __restrict__ xdblP,
                       const float* __restrict__ dtwT,
                       const float* __restrict__ dtb, float* __restrict__ dts_t,
                       float* __restrict__ bc){
  __shared__ float psum[4][44];
  int k = blockIdx.y;
  int l0 = blockIdx.x*4;
  int tid = threadIdx.x;
  for (int i=tid; i<176; i+=384){
    int li = i/44, c = i%44;
    int l = l0 + li;
    size_t o0 = ((size_t)(k)*CXP_ + c)*L_ + l;
    size_t o1 = ((size_t)(4+k)*CXP_ + c)*L_ + l;
    size_t o2 = ((size_t)(8+k)*CXP_ + c)*L_ + l;
    psum[li][c] = xdblP[o0] + xdblP[o1] + xdblP[o2];
  }
  __syncthreads();
  int d = tid;
  float w[12];
  #pragma unroll
  for (int r=0;r<R_;r++) w[r] = dtwT[((size_t)k*R_ + r)*DI_ + d];
  float bias = dtb[(size_t)k*DI_ + d];
  #pragma unroll
  for (int li=0; li<4; li++){
    float acc = bias;
    #pragma unroll
    for (int r=0;r<R_;r++) acc = fmaf(psum[li][r], w[r], acc);
    dts_t[((size_t)k*L_ + l0+li)*DI_ + d] = softplus_(acc);
  }
  if (tid < 128){
    int li = tid>>5, d2 = tid&31;
    bc[((size_t)k*L_ + l0+li)*32 + d2] = psum[li][12+d2];
  }
}

// ---------------- chunked selective scan, phase A — chunk tiles staged in LDS
// (dt,xv) packed float2 -> one b64/step; B-half only; EH packed float2 out.
__global__ __launch_bounds__(256) void k_scanA(const float* __restrict__ xst0,
                      const float* __restrict__ xst1,
                      const float* __restrict__ dts_t, const float* __restrict__ bc,
                      const float* __restrict__ Alog,
                      float2* __restrict__ eh){
  __shared__ float2 sdx[TC_][16];
  __shared__ float sb[TC_][16];
  int k = blockIdx.z;
  int d0 = blockIdx.y*16;
  int ch = blockIdx.x;
  int tid = threadIdx.x;
  int t0 = ch*TC_;
  const float* xb = (k&1) ? xst1 : xst0;
  for (int i=tid; i<TC_*16; i+=256){
    int t = i>>4, dl = i&15;
    float dtv = dts_t[((size_t)k*L_ + t0+t)*DI_ + d0+dl];
    int l = (k<2) ? (t0+t) : (1023-t0-t);
    float xvv = xb[(size_t)l*DI_ + d0+dl];
    sdx[t][dl] = make_float2(dtv, xvv);
    sb[t][dl] = bc[((size_t)k*L_ + t0+t)*32 + dl];
  }
  __syncthreads();
  int dg = tid>>4;
  int d = d0 + dg;
  int n = tid&15;
  float A = -expf(Alog[((size_t)k*DI_ + d)*NS_ + n]);
  float aL2 = A * 1.4426950408889634f;
  float h = 0.f, Ep = 1.f;
  #pragma unroll 8
  for (int t=0;t<TC_;t++){
    float2 dx = sdx[t][dg];
    float Bn = sb[t][n];
    float e = exp2f(aL2*dx.x);
    h = fmaf(e, h, dx.x*dx.y*Bn);
    Ep *= e;
  }
  size_t idx = (((size_t)k*NCH_ + ch)*DI_ + d)*NS_ + n;
  eh[idx] = make_float2(Ep, h);
}

// ---------------- phase C: carry fold (packed EH) + LDS float2 tiles + DPP rowsum
__global__ __launch_bounds__(256) void k_scanC(const float* __restrict__ xst0,
                      const float* __restrict__ xst1,
                      const float* __restrict__ dts_t, const float* __restrict__ bc,
                      const float* __restrict__ Alog, const float2* __restrict__ eh,
                      float* __restrict__ yst){
  __shared__ float2 sdx[TC_][16];
  __shared__ float2 sbc2[TC_][16];
  int k = blockIdx.z;
  int d0 = blockIdx.y*16;
  int ch = blockIdx.x;
  int tid = threadIdx.x;
  int t0 = ch*TC_;
  const float* xb = (k&1) ? xst1 : xst0;
  for (int i=tid; i<TC_*16; i+=256){
    int t = i>>4, dl = i&15;
    float dtv = dts_t[((size_t)k*L_ + t0+t)*DI_ + d0+dl];
    int l = (k<2) ? (t0+t) : (1023-t0-t);
    float xvv = xb[(size_t)l*DI_ + d0+dl];
    sdx[t][dl] = make_float2(dtv, xvv);
    const float* bcp = bc + ((size_t)k*L_ + t0+t)*32;
    sbc2[t][dl] = make_float2(bcp[dl], bcp[16+dl]);
  }
  int dg = tid>>4;
  int d = d0 + dg;
  int n = tid&15;
  float A = -expf(Alog[((size_t)k*DI_ + d)*NS_ + n]);
  float aL2 = A * 1.4426950408889634f;
  // carry-in: fold packed (E,H) aggregates of preceding chunks
  float h = 0.f;
  {
    size_t base = (size_t)k*NCH_*DI_*NS_ + (size_t)d*NS_ + n;
    const size_t cs = (size_t)DI_*NS_;
    int c = 0;
    for (; c+4<=ch; c+=4){
      float2 a0 = eh[base+(size_t)c*cs];
      float2 a1 = eh[base+(size_t)(c+1)*cs];
      float2 a2 = eh[base+(size_t)(c+2)*cs];
      float2 a3 = eh[base+(size_t)(c+3)*cs];
      h = fmaf(a0.x,h,a0.y); h = fmaf(a1.x,h,a1.y);
      h = fmaf(a2.x,h,a2.y); h = fmaf(a3.x,h,a3.y);
    }
    for (; c<ch; c++){
      float2 a = eh[base+(size_t)c*cs];
      h = fmaf(a.x, h, a.y);
    }
  }
  __syncthreads();
  float* yp = yst + ((size_t)k*L_ + t0)*DI_ + d;
  #pragma unroll 8
  for (int t=0;t<TC_;t++){
    float2 dx = sdx[t][dg];
    float2 bcv = sbc2[t][n];
    float e = exp2f(aL2*dx.x);
    h = fmaf(e, h, dx.x*dx.y*bcv.x);
    float p = rowsum16_(h*bcv.y);
    if (n==15) yp[(size_t)t*DI_] = p;
  }
}

// ---------------- merge 4 dirs + Dskip + LN + silu(z) gate; zeroes LN-sum bufs
__global__ void k_merge(const float* __restrict__ yst, const float* __restrict__ xst0,
                        const float* __restrict__ xst1,
                        const float* __restrict__ Dsk, const float* __restrict__ mw,
                        const float* __restrict__ ong, const float* __restrict__ onb,
                        const float* __restrict__ xz, float* __restrict__ out,
                        float* __restrict__ su, float* __restrict__ sq){
  int l = blockIdx.x, d = threadIdx.x;
  if (d == 0){ su[l] = 0.f; sq[l] = 0.f; }
  int T = ((l&31)<<5) | (l>>5);
  int tt[4] = { l, T, 1023-l, 1023-T };
  float xv0 = xst0[(size_t)l*DI_ + d];
  float xv1 = xst1[(size_t)T*DI_ + d];
  float v = 0.f;
  #pragma unroll
  for (int k=0;k<4;k++){
    float xk = (k&1) ? xv1 : xv0;
    v += mw[k]*(yst[(size_t)(k*L_ + tt[k])*DI_ + d] + xk*Dsk[k*DI_+d]);
  }
  float s = wsum64_(v), sqv = wsum64_(v*v);
  __shared__ float rs_[6], rq_[6];
  int lane = d&63, wid = d>>6;
  if (lane==63){ rs_[wid]=s; rq_[wid]=sqv; }
  __syncthreads();
  float ts=0.f, tq=0.f;
  #pragma unroll
  for (int i=0;i<6;i++){ ts += rs_[i]; tq += rq_[i]; }
  float mu = ts*(1.f/DI_);
  float rstd = rsqrtf(tq*(1.f/DI_) - mu*mu + 1e-5f);
  float y = (v-mu)*rstd*ong[d] + onb[d];
  float z = xz[(size_t)l*768 + DI_ + d];
  out[(size_t)l*DI_ + d] = y * silu_(z);
}

// ---------------- scpa: dual 1x1 conv + lrelu; 2px/thread; padded output + border zero
__global__ __launch_bounds__(256) void k_1x1ab(const float* __restrict__ h2,
                        const float* __restrict__ r1,
                        float* __restrict__ padA, float* __restrict__ padB){
  __shared__ float lw[1152];
  int g = blockIdx.y;
  int tid = threadIdx.x;
  for (int i=tid; i<288; i+=256)
    ((float4*)lw)[i] = ((const float4*)(r1 + (size_t)g*1152))[i];
  if (blockIdx.x == 0){
    for (int i=tid; i<6240; i+=256){
      int ch = i/520, rem = i%520;
      int row, col;
      if (rem < 132){ row = 0; col = rem; }
      else if (rem < 264){ row = 129; col = rem-132; }
      else { int rr = rem-264; row = 1 + (rr>>1); col = (rr&1) ? 129 : 0; }
      float* dst = (ch < 6) ? padA : padB;
      int c = g*6 + (ch < 6 ? ch : ch-6);
      dst[(size_t)c*PCH_ + row*132 + col] = 0.f;
    }
  }
  __syncthreads();
  int p0 = (blockIdx.x*256 + tid)*2;
  float acc[2][12];
  #pragma unroll
  for (int i=0;i<2;i++)
    #pragma unroll
    for (int o=0;o<12;o++) acc[i][o]=0.f;
  for (int c=0;c<96;c++){
    float2 v = *(const float2*)&h2[(size_t)c*HW + p0];
    float4 w0 = *(const float4*)&lw[c*12];
    float4 w1 = *(const float4*)&lw[c*12+4];
    float4 w2 = *(const float4*)&lw[c*12+8];
    acc[0][0] = fmaf(v.x, w0.x, acc[0][0]); acc[1][0] = fmaf(v.y, w0.x, acc[1][0]);
    acc[0][1] = fmaf(v.x, w0.y, acc[0][1]); acc[1][1] = fmaf(v.y, w0.y, acc[1][1]);
    acc[0][2] = fmaf(v.x, w0.z, acc[0][2]); acc[1][2] = fmaf(v.y, w0.z, acc[1][2]);
    acc[0][3] = fmaf(v.x, w0.w, acc[0][3]); acc[1][3] = fmaf(v.y, w0.w, acc[1][3]);
    acc[0][4] = fmaf(v.x, w1.x, acc[0][4]); acc[1][4] = fmaf(v.y, w1.x, acc[1][4]);
    acc[0][5] = fmaf(v.x, w1.y, acc[0][5]); acc[1][5] = fmaf(v.y, w1.y, acc[1][5]);
    acc[0][6] = fmaf(v.x, w1.z, acc[0][6]); acc[1][6] = fmaf(v.y, w1.z, acc[1][6]);
    acc[0][7] = fmaf(v.x, w1.w, acc[0][7]); acc[1][7] = fmaf(v.y, w1.w, acc[1][7]);
    acc[0][8] = fmaf(v.x, w2.x, acc[0][8]); acc[1][8] = fmaf(v.y, w2.x, acc[1][8]);
    acc[0][9] = fmaf(v.x, w2.y, acc[0][9]); acc[1][9] = fmaf(v.y, w2.y, acc[1][9]);
    acc[0][10]= fmaf(v.x, w2.z, acc[0][10]); acc[1][10]= fmaf(v.y, w2.z, acc[1][10]);
    acc[0][11]= fmaf(v.x, w2.w, acc[0][11]); acc[1][11]= fmaf(v.y, w2.w, acc[1][11]);
  }
  int row = p0>>7, col = p0&127;
  size_t pb = (size_t)(row+1)*132 + col+1;
  #pragma unroll
  for (int o=0;o<6;o++){
    size_t oa = (size_t)(g*6+o)*PCH_ + pb;
    padA[oa]   = lrelu_(acc[0][o]);
    padA[oa+1] = lrelu_(acc[1][o]);
    padB[oa]   = lrelu_(acc[0][6+o]);
    padB[oa+1] = lrelu_(acc[1][6+o]);
  }
}

// ---------------- scpa: DUAL 3x3 conv on padded inputs, 4px/thread, aligned loads,
// LDS weight broadcast; k2 gate fused into B half (writes padded bufT + its borders).
// grid (16 rowtiles, 32 = half*16+g3), tb 256
__global__ __launch_bounds__(256) void k_conv3d(const float* __restrict__ padA,
                        const float* __restrict__ padB, const float* __restrict__ rpD,
                        const float* __restrict__ k2b,
                        float* __restrict__ outA, float* __restrict__ padT){
  __shared__ float lw[1536];
  int tid = threadIdx.x;
  int y = blockIdx.y;
  int half = y >> 4;
  int g3 = y & 15;
  const float* in = half ? padB : padA;
  const float* wg = rpD + (size_t)y*1536;
  for (int i=tid; i<384; i+=256)
    ((float4*)lw)[i] = ((const float4*)wg)[i];
  if (half && blockIdx.x == 0){
    for (int i=tid; i<1560; i+=256){
      int ch = i/520, rem = i%520;
      int row, col;
      if (rem < 132){ row = 0; col = rem; }
      else if (rem < 264){ row = 129; col = rem-132; }
      else { int rr = rem-264; row = 1 + (rr>>1); col = (rr&1) ? 129 : 0; }
      padT[(size_t)(g3*3+ch)*PCH_ + row*132 + col] = 0.f;
    }
  }
  __syncthreads();
  int orow = blockIdx.x*8 + (tid>>5);
  int cx = (tid&31)*4;
  float acc[4][3], gc[4][3];
  #pragma unroll
  for (int j=0;j<4;j++)
    #pragma unroll
    for (int o=0;o<3;o++){ acc[j][o]=0.f; gc[j][o]=0.f; }
  const float* ipb = in + (size_t)orow*132 + cx;
  for (int ic=0; ic<48; ic++){
    float w[32];
    #pragma unroll
    for (int q=0;q<8;q++) *(float4*)&w[q*4] = *(const float4*)&lw[ic*32+q*4];
    const float* ip = ipb + (size_t)ic*PCH_;
    float4 a0 = *(const float4*)(ip);       float2 b0 = *(const float2*)(ip+4);
    float4 a1 = *(const float4*)(ip+132);   float2 b1 = *(const float2*)(ip+136);
    float4 a2 = *(const float4*)(ip+264);   float2 b2 = *(const float2*)(ip+268);
    float f0[6] = {a0.x,a0.y,a0.z,a0.w,b0.x,b0.y};
    float f1[6] = {a1.x,a1.y,a1.z,a1.w,b1.x,b1.y};
    float f2[6] = {a2.x,a2.y,a2.z,a2.w,b2.x,b2.y};
    #pragma unroll
    for (int o=0;o<3;o++){
      #pragma unroll
      for (int j=0;j<4;j++){
        float a = acc[j][o];
        a = fmaf(f0[j],   w[o*9+0], a);
        a = fmaf(f0[j+1], w[o*9+1], a);
        a = fmaf(f0[j+2], w[o*9+2], a);
        a = fmaf(f1[j],   w[o*9+3], a);
        a = fmaf(f1[j+1], w[o*9+4], a);
        a = fmaf(f1[j+2], w[o*9+5], a);
        a = fmaf(f2[j],   w[o*9+6], a);
        a = fmaf(f2[j+1], w[o*9+7], a);
        a = fmaf(f2[j+2], w[o*9+8], a);
        acc[j][o] = a;
      }
    }
    if (half){
      #pragma unroll
      for (int j=0;j<4;j++){
        float cv = f1[j+1];
        gc[j][0] = fmaf(cv, w[27], gc[j][0]);
        gc[j][1] = fmaf(cv, w[28], gc[j][1]);
        gc[j][2] = fmaf(cv, w[29], gc[j][2]);
      }
    }
  }
  if (!half){
    int pb = orow*128 + cx;
    #pragma unroll
    for (int o=0;o<3;o++){
      float4 ov;
      ov.x = lrelu_(acc[0][o]); ov.y = lrelu_(acc[1][o]);
      ov.z = lrelu_(acc[2][o]); ov.w = lrelu_(acc[3][o]);
      *(float4*)&outA[(size_t)(g3*3+o)*HW + pb] = ov;
    }
  } else {
    size_t pb = (size_t)(orow+1)*132 + cx + 1;
    #pragma unroll
    for (int o=0;o<3;o++){
      float bb = k2b[g3*3+o];
      float* dst = padT + (size_t)(g3*3+o)*PCH_ + pb;
      #pragma unroll
      for (int j=0;j<4;j++)
        dst[j] = acc[j][o]*sigmoid_(gc[j][o]+bb);
    }
  }
}

// ---------------- scpa: single 3x3 conv (k4 + lrelu) on padded input, 4px/thread,
// 2 oc per group; grid (16 rowtiles, 24 g2), tb 256
__global__ __launch_bounds__(256) void k_conv3(const float* __restrict__ padT,
                        const float* __restrict__ rp3, float* __restrict__ out){
  __shared__ float lw[960];
  int tid = threadIdx.x;
  int g2 = blockIdx.y;
  const float* wg = rp3 + (size_t)g2*960;
  for (int i=tid; i<240; i+=256)
    ((float4*)lw)[i] = ((const float4*)wg)[i];
  __syncthreads();
  int orow = blockIdx.x*8 + (tid>>5);
  int cx = (tid&31)*4;
  float acc[4][2];
  #pragma unroll
  for (int j=0;j<4;j++){ acc[j][0]=0.f; acc[j][1]=0.f; }
  const float* ipb = padT + (size_t)orow*132 + cx;
  for (int ic=0; ic<48; ic++){
    float w[20];
    #pragma unroll
    for (int q=0;q<5;q++) *(float4*)&w[q*4] = *(const float4*)&lw[ic*20+q*4];
    const float* ip = ipb + (size_t)ic*PCH_;
    float4 a0 = *(const float4*)(ip);       float2 b0 = *(const float2*)(ip+4);
    float4 a1 = *(const float4*)(ip+132);   float2 b1 = *(const float2*)(ip+136);
    float4 a2 = *(const float4*)(ip+264);   float2 b2 = *(const float2*)(ip+268);
    float f0[6] = {a0.x,a0.y,a0.z,a0.w,b0.x,b0.y};
    float f1[6] = {a1.x,a1.y,a1.z,a1.w,b1.x,b1.y};
    float f2[6] = {a2.x,a2.y,a2.z,a2.w,b2.x,b2.y};
    #pragma unroll
    for (int o=0;o<2;o++){
      #pragma unroll
      for (int j=0;j<4;j++){
        float a = acc[j][o];
        a = fmaf(f0[j],   w[o*9+0], a);
        a = fmaf(f0[j+1], w[o*9+1], a);
        a = fmaf(f0[j+2], w[o*9+2], a);
        a = fmaf(f1[j],   w[o*9+3], a);
        a = fmaf(f1[j+1], w[o*9+4], a);
        a = fmaf(f1[j+2], w[o*9+5], a);
        a = fmaf(f2[j],   w[o*9+6], a);
        a = fmaf(f2[j+1], w[o*9+7], a);
        a = fmaf(f2[j+2], w[o*9+8], a);
        acc[j][o] = a;
      }
    }
  }
  int pb = orow*128 + cx;
  #pragma unroll
  for (int o=0;o<2;o++){
    float4 ov;
    ov.x = lrelu_(acc[0][o]); ov.y = lrelu_(acc[1][o]);
    ov.z = lrelu_(acc[2][o]); ov.w = lrelu_(acc[3][o]);
    *(float4*)&out[(size_t)(g2*2+o)*HW + pb] = ov;
  }
}

// ---------------- final 1x1 conv + both residuals; 2px/thread; LDS weights
__global__ __launch_bounds__(256) void k_c3(const float* __restrict__ ab,
                     const float* __restrict__ r3, const float* __restrict__ h2,
                     const float* __restrict__ xsum, float* __restrict__ out){
  __shared__ float lw[1152];
  int g = blockIdx.y;
  int tid = threadIdx.x;
  for (int i=tid; i<288; i+=256)
    ((float4*)lw)[i] = ((const float4*)(r3 + (size_t)g*1152))[i];
  __syncthreads();
  int p0 = (blockIdx.x*256 + tid)*2;
  float acc[2][12];
  #pragma unroll
  for (int i=0;i<2;i++)
    #pragma unroll
    for (int o=0;o<12;o++) acc[i][o]=0.f;
  for (int j=0;j<96;j++){
    float2 v = *(const float2*)&ab[(size_t)j*HW + p0];
    float4 w0 = *(const float4*)&lw[j*12];
    float4 w1 = *(const float4*)&lw[j*12+4];
    float4 w2 = *(const float4*)&lw[j*12+8];
    acc[0][0] = fmaf(v.x, w0.x, acc[0][0]); acc[1][0] = fmaf(v.y, w0.x, acc[1][0]);
    acc[0][1] = fmaf(v.x, w0.y, acc[0][1]); acc[1][1] = fmaf(v.y, w0.y, acc[1][1]);
    acc[0][2] = fmaf(v.x, w0.z, acc[0][2]); acc[1][2] = fmaf(v.y, w0.z, acc[1][2]);
    acc[0][3] = fmaf(v.x, w0.w, acc[0][3]); acc[1][3] = fmaf(v.y, w0.w, acc[1][3]);
    acc[0][4] = fmaf(v.x, w1.x, acc[0][4]); acc[1][4] = fmaf(v.y, w1.x, acc[1][4]);
    acc[0][5] = fmaf(v.x, w1.y, acc[0][5]); acc[1][5] = fmaf(v.y, w1.y, acc[1][5]);
    acc[0][6] = fmaf(v.x, w1.z, acc[0][6]); acc[1][6] = fmaf(v.y, w1.z, acc[1][6]);
    acc[0][7] = fmaf(v.x, w1.w, acc[0][7]); acc[1][7] = fmaf(v.y, w1.w, acc[1][7]);
    acc[0][8] = fmaf(v.x, w2.x, acc[0][8]); acc[1][8] = fmaf(v.y, w2.x, acc[1][8]);
    acc[0][9] = fmaf(v.x, w2.y, acc[0][9]); acc[1][9] = fmaf(v.y, w2.y, acc[1][9]);
    acc[0][10]= fmaf(v.x, w2.z, acc[0][10]); acc[1][10]= fmaf(v.y, w2.z, acc[1][10]);
    acc[0][11]= fmaf(v.x, w2.w, acc[0][11]); acc[1][11]= fmaf(v.y, w2.w, acc[1][11]);
  }
  #pragma unroll
  for (int o=0;o<12;o++){
    size_t oi = (size_t)(g*12+o)*HW + p0;
    float2 hv = *(const float2*)&h2[oi];
    float2 sv = *(const float2*)&xsum[oi];
    float2 ov;
    ov.x = acc[0][o] + hv.x + sv.x;
    ov.y = acc[1][o] + hv.y + sv.y;
    *(float2*)&out[oi] = ov;
  }
}

extern "C" void kernel_launch(void* const* d_in, const int* in_sizes, int n_in,
                              void* d_out, int out_size, void* d_ws, size_t ws_size,
                              hipStream_t stream){
  (void)in_sizes; (void)n_in; (void)out_size; (void)ws_size;
  const float* x    = (const float*)d_in[0];
  const float* bn1g = (const float*)d_in[1];
  const float* bn1b = (const float*)d_in[2];
  const float* bn1m = (const float*)d_in[3];
  const float* bn1v = (const float*)d_in[4];
  const float* caw1 = (const float*)d_in[5];
  const float* caw2 = (const float*)d_in[6];
  const float* peW  = (const float*)d_in[7];
  const float* peb  = (const float*)d_in[8];
  const float* puW  = (const float*)d_in[9];
  const float* pub  = (const float*)d_in[10];
  const float* lng  = (const float*)d_in[11];
  const float* lnb  = (const float*)d_in[12];
  const float* inW  = (const float*)d_in[13];
  const float* convw= (const float*)d_in[14];
  const float* convb= (const float*)d_in[15];
  const float* xprojw=(const float*)d_in[16];
  const float* dtw  = (const float*)d_in[17];
  const float* dtb  = (const float*)d_in[18];
  const float* Alog = (const float*)d_in[19];
  const float* Dsk  = (const float*)d_in[20];
  const float* ong  = (const float*)d_in[21];
  const float* onb  = (const float*)d_in[22];
  const float* outW = (const float*)d_in[23];
  const float* mw   = (const float*)d_in[24];
  const float* bn2g = (const float*)d_in[25];
  const float* bn2b = (const float*)d_in[26];
  const float* bn2m = (const float*)d_in[27];
  const float* bn2v = (const float*)d_in[28];
  const float* c1a  = (const float*)d_in[29];
  const float* c1b  = (const float*)d_in[30];
  const float* k1w  = (const float*)d_in[31];
  const float* k2w  = (const float*)d_in[32];
  const float* k2b  = (const float*)d_in[33];
  const float* k3w  = (const float*)d_in[34];
  const float* k4w  = (const float*)d_in[35];
  const float* c3w  = (const float*)d_in[36];
  float* out = (float*)d_out;

  float* ws = (float*)d_ws;
  size_t off = 0;
  auto alloc = [&](size_t n){ float* p = ws + off; off += n; return p; };
  float* peWT  = alloc((size_t)1536*192);
  float* puWT  = alloc((size_t)192*1536);
  float* inWT  = alloc((size_t)8*192*768);
  float* outWT = alloc((size_t)8*384*192);
  float* bufH  = alloc((size_t)96*HW);
  float* stats = alloc(256);
  float* x2a   = alloc((size_t)1024*192);
  float* x2b   = alloc((size_t)1024*192);
  float* bufXZ = alloc((size_t)1024*768);
  float* bufXCS= alloc((size_t)384*1024);
  float* bufXST= alloc((size_t)4*1024*384);  // xst0|xst1 (half used); later ab (96ch)
  float* xdblP = alloc((size_t)12*44*1024);
  float* dts   = alloc((size_t)4*1024*384);
  float* bc    = alloc((size_t)4*1024*32);
  float* yst   = alloc((size_t)4*1024*384);
  float* bufY  = alloc((size_t)1024*384);
  float* xsum  = alloc((size_t)96*HW);
  float* h2    = alloc((size_t)96*HW);
  float* ehB   = alloc((size_t)2*K_*NCH_*DI_*NS_);  // packed (E,H) float2
  float* wpk   = alloc((size_t)K_*NCH_*DI_*NS_); // repacked weights (393216 floats)
  float* suB   = alloc(1024);
  float* sqB   = alloc(1024);
  float* padA  = alloc((size_t)48*PCH_);
  float* padB  = alloc((size_t)48*PCH_);
  float* padT  = alloc((size_t)48*PCH_);
  float* xst0  = bufXST;
  float* xst1  = bufXST + (size_t)L_*DI_;
  float2* eh   = (float2*)ehB;

  float* rpD  = wpk;                // 49152
  float* rp3  = wpk + 49152;        // 23040
  float* r1w  = wpk + 72192;        // 9216
  float* r3w  = wpk + 81408;        // 9216
  float* dtwT = wpk + 90624;        // 147456

  dim3 tb(32,8);
  k_transAll<<<3234, tb, 0, stream>>>(peW, peWT, puW, puWT, inW, inWT, outW, outWT,
                                      k1w, k3w, k2w, k4w, c1a, c1b, c3w, dtw,
                                      rpD, rp3, r1w, r3w, dtwT);

  k_bn1<<<96,256,0,stream>>>(x, bn1g, bn1b, bn1m, bn1v, bufH, stats, suB, sqB);
  k_gemmPE<<<dim3(32,6),256,0,stream>>>(bufH, peWT, peb, x2a, suB, sqB);

  float* cur = x2a; float* nxt = x2b;
  for (int b=0;b<8;b++){
    k_gemm32ln<<<dim3(32,12),256,0,stream>>>(cur, inWT+(size_t)b*192*768,
                        lng+(size_t)b*192, lnb+(size_t)b*192, suB, sqB, bufXZ, 192, 768);
    k_dwxst<<<dim3(32,12),tb,0,stream>>>(bufXZ, convw+(size_t)b*384*9,
                        convb+(size_t)b*384, bufXCS, xst0, xst1);
    k_xdblP<<<dim3(4,11,12),256,0,stream>>>(bufXCS, xprojw+(size_t)b*4*44*384, xdblP);
    k_dtbc<<<dim3(256,4),384,0,stream>>>(xdblP, dtwT+(size_t)b*18432, dtb+(size_t)b*4*384, dts, bc);
    const float* Ab = Alog + (size_t)b*4*384*16;
    k_scanA<<<dim3(NCH_,DI_/16,4),256,0,stream>>>(xst0, xst1, dts, bc, Ab, eh);
    k_scanC<<<dim3(NCH_,DI_/16,4),256,0,stream>>>(xst0, xst1, dts, bc, Ab, eh, yst);
    k_merge<<<1024,384,0,stream>>>(yst, xst0, xst1, Dsk+(size_t)b*4*384, mw+(size_t)b*4,
                                   ong+(size_t)b*384, onb+(size_t)b*384, bufXZ, bufY, suB, sqB);
    k_gemm32s<<<dim3(32,6),256,0,stream>>>(bufY, outWT+(size_t)b*384*192, cur, nxt, suB, sqB, 384, 192);
    float* t = cur; cur = nxt; nxt = t;
  }

  k_gemmPUs<<<dim3(32,24),256,0,stream>>>(cur, puWT, pub, x, bufH, stats, caw1, caw2,
                                          bn2g, bn2b, bn2m, bn2v, xsum, h2);

  float* ab = bufXST;
  k_1x1ab<<<dim3(32,8),256,0,stream>>>(h2, r1w, padA, padB);
  k_conv3d<<<dim3(16,32),256,0,stream>>>(padA, padB, rpD, k2b, ab, padT);
  k_conv3<<<dim3(16,24),256,0,stream>>>(padT, rp3, ab+(size_t)48*HW);
  k_c3<<<dim3(32,8),256,0,stream>>>(ab, r3w, h2, xsum, out);
}